// Round 12
// baseline (211.790 us; speedup 1.0000x reference)
//
#include <hip/hip_runtime.h>
#include <hip/hip_bf16.h>

typedef unsigned int uint_t;
typedef unsigned short ushort_t;
typedef __attribute__((ext_vector_type(8))) short short8;
typedef __attribute__((ext_vector_type(4))) float floatx4;

__device__ __forceinline__ float4 fma4(float4 a, float s, float4 w){
  a.x += s*w.x; a.y += s*w.y; a.z += s*w.z; a.w += s*w.w; return a;
}
__device__ __forceinline__ float4 relu4(float4 a){
  return make_float4(fmaxf(a.x,0.f),fmaxf(a.y,0.f),fmaxf(a.z,0.f),fmaxf(a.w,0.f));
}
__device__ __forceinline__ unsigned bf16rne(float f){
  unsigned u = __float_as_uint(f);
  return (u + 0x7fffu + ((u>>16)&1u)) >> 16;
}
__device__ __forceinline__ uint_t packbf(float f){
  unsigned hb = bf16rne(f);
  float hf = __uint_as_float(hb<<16);
  unsigned lb = bf16rne(f - hf);
  return (hb<<16) | lb;
}
__device__ __forceinline__ uint4 pack4(float4 v){
  uint4 u; u.x=packbf(v.x); u.y=packbf(v.y); u.z=packbf(v.z); u.w=packbf(v.w); return u;
}
__device__ __forceinline__ float unpk(uint_t u){
  return __uint_as_float(u & 0xffff0000u) + __uint_as_float(u<<16);
}
#define UNPACK8(u0,u1,hi,lo) \
  hi[0]=(short)(u0.x>>16); lo[0]=(short)u0.x; \
  hi[1]=(short)(u0.y>>16); lo[1]=(short)u0.y; \
  hi[2]=(short)(u0.z>>16); lo[2]=(short)u0.z; \
  hi[3]=(short)(u0.w>>16); lo[3]=(short)u0.w; \
  hi[4]=(short)(u1.x>>16); lo[4]=(short)u1.x; \
  hi[5]=(short)(u1.y>>16); lo[5]=(short)u1.y; \
  hi[6]=(short)(u1.z>>16); lo[6]=(short)u1.z; \
  hi[7]=(short)(u1.w>>16); lo[7]=(short)u1.w;

// Fragment-order offset: off(n,k) = (n>>4)*16*K + (k>>5)*512 + (n&15)*32 + (k&31)

// =============== K1: enc (blocks 0..511) + wl1/wr1 convert (512..639) ===============
__global__ __launch_bounds__(256) void prep_kernel(
    const float* __restrict__ obs,
    const float* __restrict__ enc_w1, const float* __restrict__ enc_b1,
    const float* __restrict__ enc_w2, const float* __restrict__ enc_b2,
    const float* __restrict__ wl1, const float* __restrict__ wr1,
    ushort_t* __restrict__ wl1Thi, ushort_t* __restrict__ wl1Tlo,
    ushort_t* __restrict__ wr1Thi, ushort_t* __restrict__ wr1Tlo,
    uint_t* __restrict__ xpk, uint_t* __restrict__ xcatpk,
    unsigned* __restrict__ adjw, int* __restrict__ aiw)
{
  const int t = threadIdx.x, bid = blockIdx.x;
  if (bid >= 512){
    __shared__ float sm[32][33];
    const int cw = bid - 512;
    const float* in; ushort_t* ohi; ushort_t* olo; int tt;
    const int K = 128, N = 512;
    if (cw < 64){ in=wl1; ohi=wl1Thi; olo=wl1Tlo; tt=cw; }
    else        { in=wr1; ohi=wr1Thi; olo=wr1Tlo; tt=cw-64; }
    const int ktiles = K>>5;
    const int kt = tt % ktiles, nt = tt / ktiles;
    const int r = t>>5, c = t&31;
    #pragma unroll
    for (int i=0;i<4;i++)
      sm[r+i*8][c] = in[(size_t)(kt*32 + r + i*8)*N + nt*32 + c];
    __syncthreads();
    #pragma unroll
    for (int i=0;i<4;i++){
      const int nl = r + i*8;
      const int n  = nt*32 + nl;
      const float f = sm[c][nl];
      const unsigned hb = bf16rne(f);
      const float hf = __uint_as_float(hb<<16);
      const unsigned lb = bf16rne(f - hf);
      const size_t off = (size_t)(n>>4)*(16*K) + (size_t)kt*512 + (size_t)(n&15)*32 + c;
      ohi[off] = (ushort_t)hb;
      olo[off] = (ushort_t)lb;
    }
    return;
  }
  __shared__ float s_pos[64];
  __shared__ float s_feats[128];
  __shared__ __align__(16) float s_h[8*132];
  __shared__ int s_ai;
  const int s = bid>>2, g = bid&3;
  const float* ob = obs + s*577;

  if (t==0){
    float a = ob[576];
    a = fminf(fmaxf(a, 0.f), 31.f);
    s_ai = (int)a;
    if (g==0) aiw[s] = (int)a;
  }
  if (t < 128){ const int n=t>>4, f=t&15; s_feats[t] = ob[(g*8+n)*18+2+f]; }
  if (g==0 && t>=128 && t<192){ const int u=t-128; s_pos[u] = ob[(u>>1)*18 + (u&1)]; }
  __syncthreads();

  if (g==0 && t < 32){
    const float px = s_pos[2*t], py = s_pos[2*t+1];
    const float R2 = 0.09f;
    unsigned mm = 0u;
    for (int j=0;j<32;j++){
      const float dx = __fsub_rn(px, s_pos[2*j]), dy = __fsub_rn(py, s_pos[2*j+1]);
      const float d2 = __fadd_rn(__fmul_rn(dx,dx), __fmul_rn(dy,dy));
      if (d2 <= R2 || j==t) mm |= (1u<<j);
    }
    adjw[s*32+t] = mm;
  }

  const int n = t>>5, c0 = (t&31)*4;
  {
    float4 a = *(const float4*)(enc_b1+c0);
    #pragma unroll
    for (int f=0; f<16; f++)
      a = fma4(a, s_feats[n*16+f], *(const float4*)(enc_w1 + f*128 + c0));
    *(float4*)&s_h[n*132+c0] = relu4(a);
  }
  __syncthreads();
  {
    float4 a = *(const float4*)(enc_b2+c0);
    for (int k=0;k<128;k+=4){
      const float4 hv = *(const float4*)&s_h[n*132+k];
      a = fma4(a, hv.x, *(const float4*)(enc_w2 + (k+0)*128 + c0));
      a = fma4(a, hv.y, *(const float4*)(enc_w2 + (k+1)*128 + c0));
      a = fma4(a, hv.z, *(const float4*)(enc_w2 + (k+2)*128 + c0));
      a = fma4(a, hv.w, *(const float4*)(enc_w2 + (k+3)*128 + c0));
    }
    a = relu4(a);
    const uint4 p = pack4(a);
    const int i = g*8 + n;
    uint_t* xp = xpk + (size_t)(s*2 + (i>>4))*2048 + (c0>>5)*512 + (i&15)*32 + (c0&31);
    *(uint4*)xp = p;
    if (i == s_ai){
      uint_t* xc = xcatpk + (size_t)(s>>4)*18432 + (c0>>5)*512 + (s&15)*32 + (c0&31);
      *(uint4*)xc = p;
    }
  }
}

// =============== K2: pa1 (blocks 0..511) + wl2/qw1/vw1 converts (512..1343), 512 threads ===============
__global__ __launch_bounds__(512) void pa1_kernel(
    const uint_t* __restrict__ xpk,
    const ushort_t* __restrict__ wl1Thi, const ushort_t* __restrict__ wl1Tlo,
    const ushort_t* __restrict__ wr1Thi, const ushort_t* __restrict__ wr1Tlo,
    const float* __restrict__ att, const float* __restrict__ bias,
    const unsigned* __restrict__ adjw, const int* __restrict__ aiw,
    const float* __restrict__ wl2, const float* __restrict__ q_w1, const float* __restrict__ v_w1,
    ushort_t* __restrict__ wl2Thi, ushort_t* __restrict__ wl2Tlo,
    ushort_t* __restrict__ qw1Thi, ushort_t* __restrict__ qw1Tlo,
    ushort_t* __restrict__ vw1Thi, ushort_t* __restrict__ vw1Tlo,
    uint_t* __restrict__ x2pk, uint_t* __restrict__ xcatpk)
{
  __shared__ __align__(16) float s_gl[32*132];
  __shared__ __align__(16) float s_glB[32*132];
  __shared__ __align__(16) float s_gr[32*132];
  __shared__ __align__(16) float s_grB[32*132];
  __shared__ __align__(16) float s_att[128];
  __shared__ __align__(16) float s_b[128];
  __shared__ float s_lg[32*33];
  __shared__ unsigned s_adj[32];
  const int t = threadIdx.x, bid = blockIdx.x;

  if (bid >= 512){
    // ---- weight transpose+convert with 512 threads (reuse s_gl as 32x33 tile) ----
    const int cw = bid - 512;
    const float* in; ushort_t* ohi; ushort_t* olo; int K, N, tt;
    if (cw < 256)      { in=wl2;  ohi=wl2Thi; olo=wl2Tlo; K=512;  N=512; tt=cw; }
    else if (cw < 544) { in=q_w1; ohi=qw1Thi; olo=qw1Tlo; K=1152; N=256; tt=cw-256; }
    else               { in=v_w1; ohi=vw1Thi; olo=vw1Tlo; K=1152; N=256; tt=cw-544; }
    const int ktiles = K>>5;
    const int kt = tt % ktiles, nt = tt / ktiles;
    const int r = t>>5, c = t&31;   // r in [0,16)
    #pragma unroll
    for (int i=0;i<2;i++)
      s_gl[(r+i*16)*33 + c] = in[(size_t)(kt*32 + r + i*16)*N + nt*32 + c];
    __syncthreads();
    #pragma unroll
    for (int i=0;i<2;i++){
      const int nl = r + i*16;
      const int n  = nt*32 + nl;
      const float f = s_gl[c*33 + nl];
      const unsigned hb = bf16rne(f);
      const float hf = __uint_as_float(hb<<16);
      const unsigned lb = bf16rne(f - hf);
      const size_t off = (size_t)(n>>4)*(16*K) + (size_t)kt*512 + (size_t)(n&15)*32 + c;
      ohi[off] = (ushort_t)hb;
      olo[off] = (ushort_t)lb;
    }
    return;
  }

  const int s = bid >> 2, h = bid & 3;
  const int w = t>>6, lane = t&63, m = lane&15, quad = lane>>4;
  const int ww = w&3, khalf = w>>2;

  if (t < 128){ s_att[t] = att[h*128 + t]; s_b[t] = bias[h*128 + t]; }
  if (t >= 224 && t < 256) s_adj[t-224] = adjw[s*32 + (t-224)];
  const int ai = aiw[s];

  // ---- MFMA: ww<2 -> gl cols (ww&1)*64..+64 ; ww>=2 -> gr ; khalf splits kc {0,1}/{2,3} ----
  const ushort_t* Bhi = (ww<2) ? wl1Thi : wr1Thi;
  const ushort_t* Blo = (ww<2) ? wl1Tlo : wr1Tlo;
  const int nbase = h*8 + (ww&1)*4;
  const int kcb = khalf*2;
  const uint_t* a0p = xpk + (size_t)(s*2+0)*2048 + m*32 + quad*8 + kcb*512;
  const uint_t* a1p = xpk + (size_t)(s*2+1)*2048 + m*32 + quad*8 + kcb*512;
  const ushort_t* bp0 = Bhi + (size_t)(nbase+0)*2048 + m*32 + quad*8 + kcb*512;
  const ushort_t* bp1 = Bhi + (size_t)(nbase+1)*2048 + m*32 + quad*8 + kcb*512;
  const ushort_t* bp2 = Bhi + (size_t)(nbase+2)*2048 + m*32 + quad*8 + kcb*512;
  const ushort_t* bp3 = Bhi + (size_t)(nbase+3)*2048 + m*32 + quad*8 + kcb*512;
  const size_t lod = (size_t)(Blo - Bhi);
  floatx4 acc[2][4];
  #pragma unroll
  for (int i=0;i<2;i++)
    #pragma unroll
    for (int j=0;j<4;j++) acc[i][j] = (floatx4){0.f,0.f,0.f,0.f};

  #pragma unroll
  for (int kc=0; kc<2; kc++){
    const uint4 u00 = *(const uint4*)(a0p + kc*512);
    const uint4 u01 = *(const uint4*)(a0p + kc*512 + 4);
    const uint4 u10 = *(const uint4*)(a1p + kc*512);
    const uint4 u11 = *(const uint4*)(a1p + kc*512 + 4);
    short8 ahi0, alo0, ahi1, alo1;
    UNPACK8(u00,u01,ahi0,alo0)
    UNPACK8(u10,u11,ahi1,alo1)
    const ushort_t* bps[4] = {bp0, bp1, bp2, bp3};
    #pragma unroll
    for (int nt=0; nt<4; nt++){
      const short8 bh = *(const short8*)(bps[nt] + kc*512);
      const short8 bl = *(const short8*)(bps[nt] + kc*512 + lod);
      acc[0][nt] = __builtin_amdgcn_mfma_f32_16x16x32_bf16(ahi0, bh, acc[0][nt], 0,0,0);
      acc[0][nt] = __builtin_amdgcn_mfma_f32_16x16x32_bf16(ahi0, bl, acc[0][nt], 0,0,0);
      acc[0][nt] = __builtin_amdgcn_mfma_f32_16x16x32_bf16(alo0, bh, acc[0][nt], 0,0,0);
      acc[1][nt] = __builtin_amdgcn_mfma_f32_16x16x32_bf16(ahi1, bh, acc[1][nt], 0,0,0);
      acc[1][nt] = __builtin_amdgcn_mfma_f32_16x16x32_bf16(ahi1, bl, acc[1][nt], 0,0,0);
      acc[1][nt] = __builtin_amdgcn_mfma_f32_16x16x32_bf16(alo1, bh, acc[1][nt], 0,0,0);
    }
  }
  {
    float* dst = (ww<2) ? (khalf ? s_glB : s_gl) : (khalf ? s_grB : s_gr);
    const int colbase = (ww&1)*64;
    #pragma unroll
    for (int nt=0; nt<4; nt++){
      const int col = colbase + nt*16 + m;
      #pragma unroll
      for (int r=0;r<4;r++){
        dst[(quad*4+r)*132 + col]      = acc[0][nt][r];
        dst[(16+quad*4+r)*132 + col]   = acc[1][nt][r];
      }
    }
  }
  __syncthreads();
  for (int e=t; e<32*132; e+=512){
    s_gl[e] += s_glB[e];
    s_gr[e] += s_grB[e];
  }
  __syncthreads();

  // ---- logits ----
  {
    const int i = t>>4, jb = t&15;
    float lacc[2] = {0.f,0.f};
    for (int c=0;c<128;c+=4){
      const float4 g = *(const float4*)&s_gr[i*132+c];
      const float4 a = *(const float4*)&s_att[c];
      #pragma unroll
      for (int mm=0;mm<2;mm++){
        const float4 gj = *(const float4*)&s_gl[(jb+16*mm)*132 + c];
        float ex = g.x+gj.x; ex = fmaxf(ex, 0.2f*ex);
        float ey = g.y+gj.y; ey = fmaxf(ey, 0.2f*ey);
        float ez = g.z+gj.z; ez = fmaxf(ez, 0.2f*ez);
        float ew = g.w+gj.w; ew = fmaxf(ew, 0.2f*ew);
        lacc[mm] += ex*a.x + ey*a.y + ez*a.z + ew*a.w;
      }
    }
    s_lg[i*33 + jb]      = lacc[0];
    s_lg[i*33 + jb + 16] = lacc[1];
  }
  __syncthreads();

  // ---- masked softmax ----
  #pragma unroll
  for (int rnd=0; rnd<2; rnd++){
    const int i = rnd*16 + (t>>5), j = t&31;
    const float lg = s_lg[i*33+j];
    const bool ok = (s_adj[i]>>j)&1u;
    float v = ok ? lg : -3.0e38f;
    #pragma unroll
    for (int d_=16; d_; d_>>=1) v = fmaxf(v, __shfl_xor(v, d_, 32));
    const float e = ok ? __expf(lg - v) : 0.f;
    float sum = e;
    #pragma unroll
    for (int d_=16; d_; d_>>=1) sum += __shfl_xor(sum, d_, 32);
    s_lg[i*33+j] = e / sum;
  }
  __syncthreads();

  // ---- aggregate -> packed x2 + tap ----
  {
    const int i = t>>4, c0 = (t&15)*8;
    float4 o0 = make_float4(0.f,0.f,0.f,0.f), o1 = o0;
    for (int j=0;j<32;j++){
      const float al = s_lg[i*33+j];
      o0 = fma4(o0, al, *(const float4*)&s_gl[j*132 + c0]);
      o1 = fma4(o1, al, *(const float4*)&s_gl[j*132 + c0 + 4]);
    }
    const float4 b0 = *(const float4*)&s_b[c0];
    const float4 b1 = *(const float4*)&s_b[c0+4];
    o0 = relu4(make_float4(o0.x+b0.x, o0.y+b0.y, o0.z+b0.z, o0.w+b0.w));
    o1 = relu4(make_float4(o1.x+b1.x, o1.y+b1.y, o1.z+b1.z, o1.w+b1.w));
    const uint4 p0 = pack4(o0), p1 = pack4(o1);
    const int kb = h*128 + c0;
    uint_t* xp = x2pk + (size_t)(s*2 + (i>>4))*8192 + (kb>>5)*512 + (i&15)*32 + (kb&31);
    *(uint4*)&xp[0] = p0;
    *(uint4*)&xp[4] = p1;
    if (i == ai){
      const int kk = 128 + kb;
      uint_t* tp = xcatpk + (size_t)(s>>4)*18432 + (kk>>5)*512 + (s&15)*32 + (kk&31);
      *(uint4*)&tp[0] = p0;
      *(uint4*)&tp[4] = p1;
    }
  }
}

// =============== K3: fused proj2 + grtap + attn2, block = (s,h), 512 threads ===============
__global__ __launch_bounds__(512) void pa2_kernel(
    const uint_t* __restrict__ x2pk,
    const ushort_t* __restrict__ wl2Thi, const ushort_t* __restrict__ wl2Tlo,
    const float* __restrict__ wr2f,
    const float* __restrict__ att2, const float* __restrict__ bias2,
    const unsigned* __restrict__ adjw, const int* __restrict__ aiw,
    uint_t* __restrict__ xcatpk)
{
  __shared__ __align__(16) float s_gl[32*132];
  __shared__ __align__(16) float s_glB[32*132];
  __shared__ __align__(16) float s_xt[512];
  __shared__ __align__(16) float s_p2[4*128];
  __shared__ __align__(16) float s_at[128];
  __shared__ __align__(16) float s_bb[128];
  __shared__ float s_lg[32];
  __shared__ float s_al[32];
  const int t = threadIdx.x;
  const int s = blockIdx.x >> 2, h = blockIdx.x & 3;
  const int w = t>>6, lane = t&63, m = lane&15, quad = lane>>4;
  const int ww = w&3, khalf = w>>2;
  const int ai = aiw[s];
  const unsigned arow = adjw[s*32+ai];

  {
    const int kk = 128 + t;
    s_xt[t] = unpk(xcatpk[(size_t)(s>>4)*18432 + (kk>>5)*512 + (s&15)*32 + (kk&31)]);
  }
  if (t < 128){ s_at[t] = att2[h*128+t]; s_bb[t] = bias2[h*128+t]; }
  __syncthreads();

  {
    const int c = t&127, q4 = t>>7;
    const float* wp = wr2f + (size_t)(q4*128)*512 + h*128 + c;
    float ga = 0.f;
    #pragma unroll 8
    for (int k=0;k<128;k++) ga += s_xt[q4*128 + k] * wp[(size_t)k*512];
    s_p2[q4*128 + c] = ga;
  }

  const int kcb = khalf*8;
  const uint_t* a0p = x2pk + (size_t)(s*2+0)*8192 + m*32 + quad*8 + kcb*512;
  const uint_t* a1p = x2pk + (size_t)(s*2+1)*8192 + m*32 + quad*8 + kcb*512;
  const ushort_t* bq0 = wl2Thi + (size_t)(h*8 + ww*2+0)*8192 + m*32 + quad*8 + kcb*512;
  const ushort_t* bq1 = wl2Thi + (size_t)(h*8 + ww*2+1)*8192 + m*32 + quad*8 + kcb*512;
  const size_t lod = (size_t)(wl2Tlo - wl2Thi);
  floatx4 acc[2][2];
  #pragma unroll
  for (int i=0;i<2;i++){ acc[i][0] = (floatx4){0.f,0.f,0.f,0.f}; acc[i][1] = acc[i][0]; }
  #pragma unroll 4
  for (int kc=0; kc<8; kc++){
    const uint4 u00 = *(const uint4*)(a0p + kc*512);
    const uint4 u01 = *(const uint4*)(a0p + kc*512 + 4);
    const uint4 u10 = *(const uint4*)(a1p + kc*512);
    const uint4 u11 = *(const uint4*)(a1p + kc*512 + 4);
    short8 ahi0, alo0, ahi1, alo1;
    UNPACK8(u00,u01,ahi0,alo0)
    UNPACK8(u10,u11,ahi1,alo1)
    {
      const short8 bh = *(const short8*)(bq0 + kc*512);
      const short8 bl = *(const short8*)(bq0 + kc*512 + lod);
      acc[0][0] = __builtin_amdgcn_mfma_f32_16x16x32_bf16(ahi0, bh, acc[0][0], 0,0,0);
      acc[0][0] = __builtin_amdgcn_mfma_f32_16x16x32_bf16(ahi0, bl, acc[0][0], 0,0,0);
      acc[0][0] = __builtin_amdgcn_mfma_f32_16x16x32_bf16(alo0, bh, acc[0][0], 0,0,0);
      acc[1][0] = __builtin_amdgcn_mfma_f32_16x16x32_bf16(ahi1, bh, acc[1][0], 0,0,0);
      acc[1][0] = __builtin_amdgcn_mfma_f32_16x16x32_bf16(ahi1, bl, acc[1][0], 0,0,0);
      acc[1][0] = __builtin_amdgcn_mfma_f32_16x16x32_bf16(alo1, bh, acc[1][0], 0,0,0);
    }
    {
      const short8 bh = *(const short8*)(bq1 + kc*512);
      const short8 bl = *(const short8*)(bq1 + kc*512 + lod);
      acc[0][1] = __builtin_amdgcn_mfma_f32_16x16x32_bf16(ahi0, bh, acc[0][1], 0,0,0);
      acc[0][1] = __builtin_amdgcn_mfma_f32_16x16x32_bf16(ahi0, bl, acc[0][1], 0,0,0);
      acc[0][1] = __builtin_amdgcn_mfma_f32_16x16x32_bf16(alo0, bh, acc[0][1], 0,0,0);
      acc[1][1] = __builtin_amdgcn_mfma_f32_16x16x32_bf16(ahi1, bh, acc[1][1], 0,0,0);
      acc[1][1] = __builtin_amdgcn_mfma_f32_16x16x32_bf16(ahi1, bl, acc[1][1], 0,0,0);
      acc[1][1] = __builtin_amdgcn_mfma_f32_16x16x32_bf16(alo1, bh, acc[1][1], 0,0,0);
    }
  }
  {
    float* dst = khalf ? s_glB : s_gl;
    const int colbase = ww*32;
    #pragma unroll
    for (int nt=0; nt<2; nt++){
      const int col = colbase + nt*16 + m;
      #pragma unroll
      for (int r=0;r<4;r++){
        dst[(quad*4+r)*132 + col]    = acc[0][nt][r];
        dst[(16+quad*4+r)*132 + col] = acc[1][nt][r];
      }
    }
  }
  __syncthreads();
  for (int e=t; e<32*132; e+=512) s_gl[e] += s_glB[e];
  if (t < 128) s_p2[t] = s_p2[t] + s_p2[128+t] + s_p2[256+t] + s_p2[384+t];
  __syncthreads();

  if (t < 256){
    const int j = t>>3, pq = t&7;
    float sum = 0.f;
    #pragma unroll
    for (int q=0;q<4;q++){
      const int c = pq*16 + q*4;
      const float4 g = *(const float4*)&s_gl[j*132 + c];
      const float4 r = *(const float4*)&s_p2[c];
      const float4 a = *(const float4*)&s_at[c];
      float e0 = r.x+g.x; e0 = fmaxf(e0, 0.2f*e0);
      float e1 = r.y+g.y; e1 = fmaxf(e1, 0.2f*e1);
      float e2 = r.z+g.z; e2 = fmaxf(e2, 0.2f*e2);
      float e3 = r.w+g.w; e3 = fmaxf(e3, 0.2f*e3);
      sum += e0*a.x + e1*a.y + e2*a.z + e3*a.w;
    }
    sum += __shfl_xor(sum,1,64);
    sum += __shfl_xor(sum,2,64);
    sum += __shfl_xor(sum,4,64);
    if (pq==0) s_lg[j] = sum;
  }
  __syncthreads();
  if (t < 32){
    const float lg = s_lg[t];
    const bool ok = (arow>>t)&1u;
    float v = ok ? lg : -3.0e38f;
    #pragma unroll
    for (int d_=16; d_; d_>>=1) v = fmaxf(v, __shfl_xor(v, d_, 32));
    const float e = ok ? __expf(lg - v) : 0.f;
    float sm = e;
    #pragma unroll
    for (int d_=16; d_; d_>>=1) sm += __shfl_xor(sm, d_, 32);
    s_al[t] = e / sm;
  }
  __syncthreads();
  if (t < 128){
    float acc2 = 0.f;
    #pragma unroll 8
    for (int j=0;j<32;j++) acc2 += s_al[j] * s_gl[j*132 + t];
    const int kk = 640 + h*128 + t;
    xcatpk[(size_t)(s>>4)*18432 + (kk>>5)*512 + (s&15)*32 + (kk&31)]
        = packbf(fmaxf(acc2 + s_bb[t], 0.f));
  }
}

// =============== K4: fused heads GEMM + epilogue + final, 8 blocks x 512 ===============
__global__ __launch_bounds__(512) void heads_kernel(
    const uint_t* __restrict__ xcatpk,
    const ushort_t* __restrict__ qw1Thi, const ushort_t* __restrict__ qw1Tlo,
    const ushort_t* __restrict__ vw1Thi, const ushort_t* __restrict__ vw1Tlo,
    const float* __restrict__ q_b1, const float* __restrict__ q_w2, const float* __restrict__ q_b2,
    const float* __restrict__ v_b1, const float* __restrict__ v_w2, const float* __restrict__ v_b2,
    float* __restrict__ out)
{
  __shared__ __align__(16) float s_C[16*520];   // 16 samples x 512 cols (stride 520)
  const int t = threadIdx.x, rt = blockIdx.x;   // rt: row-block of 16 samples
  const int w = t>>6, lane = t&63, m = lane&15, quad = lane>>4;

  // wave w -> ntiles w*4 .. w*4+3 (ntile<16: q cols, else v cols). lod identical for q/v.
  const size_t lod = (size_t)(qw1Tlo - qw1Thi);
  const uint_t* ap = xcatpk + (size_t)rt*18432 + m*32 + quad*8;
  const ushort_t* bps[4];
  #pragma unroll
  for (int nt=0; nt<4; nt++){
    const int ntg = w*4 + nt;
    const ushort_t* Bhi = (ntg < 16) ? qw1Thi : vw1Thi;
    const int cbrow = (ntg < 16) ? ntg : (ntg - 16);
    bps[nt] = Bhi + (size_t)cbrow*18432 + m*32 + quad*8;
  }
  floatx4 acc[4];
  #pragma unroll
  for (int i=0;i<4;i++) acc[i] = (floatx4){0.f,0.f,0.f,0.f};
  for (int kc=0; kc<36; kc++){
    const uint4 ua0 = *(const uint4*)(ap);
    const uint4 ua1 = *(const uint4*)(ap+4);
    ap += 512;
    short8 ahi, alo;
    UNPACK8(ua0,ua1,ahi,alo)
    #pragma unroll
    for (int nt=0; nt<4; nt++){
      const short8 bh = *(const short8*)(bps[nt]);
      const short8 bl = *(const short8*)(bps[nt] + lod);
      acc[nt] = __builtin_amdgcn_mfma_f32_16x16x32_bf16(ahi, bh, acc[nt], 0,0,0);
      acc[nt] = __builtin_amdgcn_mfma_f32_16x16x32_bf16(ahi, bl, acc[nt], 0,0,0);
      acc[nt] = __builtin_amdgcn_mfma_f32_16x16x32_bf16(alo, bh, acc[nt], 0,0,0);
      bps[nt] += 512;
    }
  }
  #pragma unroll
  for (int nt=0; nt<4; nt++){
    const int colg = (w*4 + nt)*16 + m;   // 0..511 (q: 0..255, v: 256..511)
    #pragma unroll
    for (int r=0;r<4;r++)
      s_C[(quad*4+r)*520 + colg] = acc[nt][r];
  }
  __syncthreads();

  // epilogue: sample s16 = t>>5, thread j = t&31 handles cols j*8..j*8+7
  {
    const int s16 = t>>5, j = t&31;
    float pq[5] = {0.f,0.f,0.f,0.f,0.f};
    float pv = 0.f;
    #pragma unroll
    for (int cc=0; cc<8; cc++){
      const int c = j*8 + cc;
      const float hq = fmaxf(s_C[s16*520 + c]       + q_b1[c], 0.f);
      const float hv = fmaxf(s_C[s16*520 + 256 + c] + v_b1[c], 0.f);
      #pragma unroll
      for (int o=0;o<5;o++) pq[o] += hq * q_w2[c*5+o];
      pv += hv * v_w2[c];
    }
    #pragma unroll
    for (int d_=16; d_; d_>>=1){
      #pragma unroll
      for (int o=0;o<5;o++) pq[o] += __shfl_xor(pq[o], d_, 32);
      pv += __shfl_xor(pv, d_, 32);
    }
    if (j == 0){
      const float q0 = pq[0]+q_b2[0], q1 = pq[1]+q_b2[1], q2 = pq[2]+q_b2[2],
                  q3 = pq[3]+q_b2[3], q4 = pq[4]+q_b2[4];
      const float mean = (q0+q1+q2+q3+q4) / 5.0f;
      const float v = pv + v_b2[0];
      const int s = rt*16 + s16;
      out[s*5+0] = q0 - mean + v;
      out[s*5+1] = q1 - mean + v;
      out[s*5+2] = q2 - mean + v;
      out[s*5+3] = q3 - mean + v;
      out[s*5+4] = q4 - mean + v;
    }
  }
}

extern "C" void kernel_launch(void* const* d_in, const int* in_sizes, int n_in,
                              void* d_out, int out_size, void* d_ws, size_t ws_size,
                              hipStream_t stream) {
  (void)n_in; (void)out_size; (void)ws_size;
  const float* obs    = (const float*)d_in[0];
  const float* enc_w1 = (const float*)d_in[1];
  const float* enc_b1 = (const float*)d_in[2];
  const float* enc_w2 = (const float*)d_in[3];
  const float* enc_b2 = (const float*)d_in[4];
  const float* wl1    = (const float*)d_in[5];
  const float* wr1    = (const float*)d_in[6];
  const float* att1   = (const float*)d_in[7];
  const float* bias1  = (const float*)d_in[8];
  const float* wl2    = (const float*)d_in[9];
  const float* wr2    = (const float*)d_in[10];
  const float* att2   = (const float*)d_in[11];
  const float* bias2  = (const float*)d_in[12];
  const float* q_w1   = (const float*)d_in[13];
  const float* q_b1   = (const float*)d_in[14];
  const float* q_w2   = (const float*)d_in[15];
  const float* q_b2   = (const float*)d_in[16];
  const float* v_w1   = (const float*)d_in[17];
  const float* v_b1   = (const float*)d_in[18];
  const float* v_w2   = (const float*)d_in[19];
  const float* v_b2   = (const float*)d_in[20];

  char* ws = (char*)d_ws;
  uint_t*   x_pk    = (uint_t*)  (ws + 0);
  uint_t*   xcat_pk = (uint_t*)  (ws + 2097152);
  unsigned* adjw    = (unsigned*)(ws + 2686976);
  int*      aiw     = (int*)     (ws + 2703360);
  uint_t*   x2_pk   = (uint_t*)  (ws + 2703872);
  ushort_t* wl1Thi  = (ushort_t*)(ws + 11092480);
  ushort_t* wl1Tlo  = (ushort_t*)(ws + 11223552);
  ushort_t* wr1Thi  = (ushort_t*)(ws + 11354624);
  ushort_t* wr1Tlo  = (ushort_t*)(ws + 11485696);
  ushort_t* wl2Thi  = (ushort_t*)(ws + 11616768);
  ushort_t* wl2Tlo  = (ushort_t*)(ws + 12141056);
  ushort_t* qw1Thi  = (ushort_t*)(ws + 12665344);
  ushort_t* qw1Tlo  = (ushort_t*)(ws + 13255168);
  ushort_t* vw1Thi  = (ushort_t*)(ws + 13844992);
  ushort_t* vw1Tlo  = (ushort_t*)(ws + 14434816);

  const int bs = in_sizes[0] / 577;   // 128

  // K1: enc (512 blocks) + wl1/wr1 converts (128 blocks)
  prep_kernel<<<512 + 128, 256, 0, stream>>>(obs, enc_w1, enc_b1, enc_w2, enc_b2,
      wl1, wr1, wl1Thi, wl1Tlo, wr1Thi, wr1Tlo,
      x_pk, xcat_pk, adjw, aiw);

  // K2: pa1 (512 blocks) + wl2/qw1/vw1 converts (832 blocks), all 512 threads
  pa1_kernel<<<512 + 832, 512, 0, stream>>>(x_pk, wl1Thi, wl1Tlo, wr1Thi, wr1Tlo,
      att1, bias1, adjw, aiw,
      wl2, q_w1, v_w1, wl2Thi, wl2Tlo, qw1Thi, qw1Tlo, vw1Thi, vw1Tlo,
      x2_pk, xcat_pk);

  // K3: pa2
  pa2_kernel<<<bs*4, 512, 0, stream>>>(x2_pk, wl2Thi, wl2Tlo, wr2,
                                       att2, bias2, adjw, aiw, xcat_pk);

  // K4: fused heads
  heads_kernel<<<8, 512, 0, stream>>>(xcat_pk, qw1Thi, qw1Tlo, vw1Thi, vw1Tlo,
                                      q_b1, q_w2, q_b2, v_b1, v_w2, v_b2,
                                      (float*)d_out);
}

// Round 13
// 181.236 us; speedup vs baseline: 1.1686x; 1.1686x over previous
//
#include <hip/hip_runtime.h>
#include <hip/hip_bf16.h>

typedef unsigned int uint_t;
typedef unsigned short ushort_t;
typedef __attribute__((ext_vector_type(8))) short short8;
typedef __attribute__((ext_vector_type(4))) float floatx4;

__device__ __forceinline__ float4 fma4(float4 a, float s, float4 w){
  a.x += s*w.x; a.y += s*w.y; a.z += s*w.z; a.w += s*w.w; return a;
}
__device__ __forceinline__ float4 relu4(float4 a){
  return make_float4(fmaxf(a.x,0.f),fmaxf(a.y,0.f),fmaxf(a.z,0.f),fmaxf(a.w,0.f));
}
__device__ __forceinline__ unsigned bf16rne(float f){
  unsigned u = __float_as_uint(f);
  return (u + 0x7fffu + ((u>>16)&1u)) >> 16;
}
__device__ __forceinline__ uint_t packbf(float f){
  unsigned hb = bf16rne(f);
  float hf = __uint_as_float(hb<<16);
  unsigned lb = bf16rne(f - hf);
  return (hb<<16) | lb;
}
__device__ __forceinline__ uint4 pack4(float4 v){
  uint4 u; u.x=packbf(v.x); u.y=packbf(v.y); u.z=packbf(v.z); u.w=packbf(v.w); return u;
}
__device__ __forceinline__ float unpk(uint_t u){
  return __uint_as_float(u & 0xffff0000u) + __uint_as_float(u<<16);
}
#define UNPACK8(u0,u1,hi,lo) \
  hi[0]=(short)(u0.x>>16); lo[0]=(short)u0.x; \
  hi[1]=(short)(u0.y>>16); lo[1]=(short)u0.y; \
  hi[2]=(short)(u0.z>>16); lo[2]=(short)u0.z; \
  hi[3]=(short)(u0.w>>16); lo[3]=(short)u0.w; \
  hi[4]=(short)(u1.x>>16); lo[4]=(short)u1.x; \
  hi[5]=(short)(u1.y>>16); lo[5]=(short)u1.y; \
  hi[6]=(short)(u1.z>>16); lo[6]=(short)u1.z; \
  hi[7]=(short)(u1.w>>16); lo[7]=(short)u1.w;

// Fragment-order offset: off(n,k) = (n>>4)*16*K + (k>>5)*512 + (n&15)*32 + (k&31)

// heads GEMM K-split body: block (ks, ct), 512 threads (8 waves = 8 row-blocks of 16).
// Computes partial [128 x 64cols] over kc = ks*6 .. ks*6+5 -> part[ks].
__device__ __forceinline__ void hgemm_body(
    const uint_t* __restrict__ xcatpk,
    const ushort_t* __restrict__ qw1Thi, const ushort_t* __restrict__ qw1Tlo,
    const ushort_t* __restrict__ vw1Thi, const ushort_t* __restrict__ vw1Tlo,
    float* __restrict__ part, int ks, int ct, int t)
{
  const int w = t>>6, lane = t&63, m = lane&15, quad = lane>>4;
  const ushort_t* Bhi = (ct<4) ? qw1Thi : vw1Thi;
  const ushort_t* Blo = (ct<4) ? qw1Tlo : vw1Tlo;
  const int cbl = (ct<4) ? ct*64 : (ct-4)*64;      // local col base in q/v weight
  const int cbg = (ct<4) ? ct*64 : 256 + (ct-4)*64; // global col base in C
  const uint_t* ap = xcatpk + (size_t)w*18432 + m*32 + quad*8 + (size_t)(ks*6)*512;
  const ushort_t* bp0 = Bhi + (size_t)((cbl>>4)+0)*18432 + m*32 + quad*8 + (size_t)(ks*6)*512;
  const ushort_t* bp1 = Bhi + (size_t)((cbl>>4)+1)*18432 + m*32 + quad*8 + (size_t)(ks*6)*512;
  const ushort_t* bp2 = Bhi + (size_t)((cbl>>4)+2)*18432 + m*32 + quad*8 + (size_t)(ks*6)*512;
  const ushort_t* bp3 = Bhi + (size_t)((cbl>>4)+3)*18432 + m*32 + quad*8 + (size_t)(ks*6)*512;
  const size_t lod = (size_t)(qw1Tlo - qw1Thi);   // identical layout gap for q and v
  floatx4 acc[4];
  #pragma unroll
  for (int i=0;i<4;i++) acc[i] = (floatx4){0.f,0.f,0.f,0.f};
  #pragma unroll
  for (int kc=0; kc<6; kc++){
    const uint4 ua0 = *(const uint4*)(ap);
    const uint4 ua1 = *(const uint4*)(ap+4);
    ap += 512;
    short8 ahi, alo;
    UNPACK8(ua0,ua1,ahi,alo)
    const ushort_t* bps[4] = {bp0, bp1, bp2, bp3};
    #pragma unroll
    for (int nt=0; nt<4; nt++){
      const short8 bh = *(const short8*)(bps[nt] + kc*512);
      const short8 bl = *(const short8*)(bps[nt] + kc*512 + lod);
      acc[nt] = __builtin_amdgcn_mfma_f32_16x16x32_bf16(ahi, bh, acc[nt], 0,0,0);
      acc[nt] = __builtin_amdgcn_mfma_f32_16x16x32_bf16(ahi, bl, acc[nt], 0,0,0);
      acc[nt] = __builtin_amdgcn_mfma_f32_16x16x32_bf16(alo, bh, acc[nt], 0,0,0);
    }
  }
  float* pdst = part + (size_t)ks*65536;
  const int crow0 = w*16 + quad*4;
  #pragma unroll
  for (int nt=0; nt<4; nt++){
    const int col = cbg + nt*16 + m;
    #pragma unroll
    for (int r=0;r<4;r++)
      pdst[(size_t)(crow0 + r)*512 + col] = acc[nt][r];
  }
}

// =============== K1: enc (blocks 0..511) + wl1/wr1 convert (512..639) ===============
__global__ __launch_bounds__(256) void prep_kernel(
    const float* __restrict__ obs,
    const float* __restrict__ enc_w1, const float* __restrict__ enc_b1,
    const float* __restrict__ enc_w2, const float* __restrict__ enc_b2,
    const float* __restrict__ wl1, const float* __restrict__ wr1,
    ushort_t* __restrict__ wl1Thi, ushort_t* __restrict__ wl1Tlo,
    ushort_t* __restrict__ wr1Thi, ushort_t* __restrict__ wr1Tlo,
    uint_t* __restrict__ xpk, uint_t* __restrict__ xcatpk,
    unsigned* __restrict__ adjw, int* __restrict__ aiw)
{
  const int t = threadIdx.x, bid = blockIdx.x;
  if (bid >= 512){
    __shared__ float sm[32][33];
    const int cw = bid - 512;
    const float* in; ushort_t* ohi; ushort_t* olo; int tt;
    const int K = 128, N = 512;
    if (cw < 64){ in=wl1; ohi=wl1Thi; olo=wl1Tlo; tt=cw; }
    else        { in=wr1; ohi=wr1Thi; olo=wr1Tlo; tt=cw-64; }
    const int ktiles = K>>5;
    const int kt = tt % ktiles, nt = tt / ktiles;
    const int r = t>>5, c = t&31;
    #pragma unroll
    for (int i=0;i<4;i++)
      sm[r+i*8][c] = in[(size_t)(kt*32 + r + i*8)*N + nt*32 + c];
    __syncthreads();
    #pragma unroll
    for (int i=0;i<4;i++){
      const int nl = r + i*8;
      const int n  = nt*32 + nl;
      const float f = sm[c][nl];
      const unsigned hb = bf16rne(f);
      const float hf = __uint_as_float(hb<<16);
      const unsigned lb = bf16rne(f - hf);
      const size_t off = (size_t)(n>>4)*(16*K) + (size_t)kt*512 + (size_t)(n&15)*32 + c;
      ohi[off] = (ushort_t)hb;
      olo[off] = (ushort_t)lb;
    }
    return;
  }
  __shared__ float s_pos[64];
  __shared__ float s_feats[128];
  __shared__ __align__(16) float s_h[8*132];
  __shared__ int s_ai;
  const int s = bid>>2, g = bid&3;
  const float* ob = obs + s*577;

  if (t==0){
    float a = ob[576];
    a = fminf(fmaxf(a, 0.f), 31.f);
    s_ai = (int)a;
    if (g==0) aiw[s] = (int)a;
  }
  if (t < 128){ const int n=t>>4, f=t&15; s_feats[t] = ob[(g*8+n)*18+2+f]; }
  if (g==0 && t>=128 && t<192){ const int u=t-128; s_pos[u] = ob[(u>>1)*18 + (u&1)]; }
  __syncthreads();

  if (g==0 && t < 32){
    const float px = s_pos[2*t], py = s_pos[2*t+1];
    const float R2 = 0.09f;
    unsigned mm = 0u;
    for (int j=0;j<32;j++){
      const float dx = __fsub_rn(px, s_pos[2*j]), dy = __fsub_rn(py, s_pos[2*j+1]);
      const float d2 = __fadd_rn(__fmul_rn(dx,dx), __fmul_rn(dy,dy));
      if (d2 <= R2 || j==t) mm |= (1u<<j);
    }
    adjw[s*32+t] = mm;
  }

  const int n = t>>5, c0 = (t&31)*4;
  {
    float4 a = *(const float4*)(enc_b1+c0);
    #pragma unroll
    for (int f=0; f<16; f++)
      a = fma4(a, s_feats[n*16+f], *(const float4*)(enc_w1 + f*128 + c0));
    *(float4*)&s_h[n*132+c0] = relu4(a);
  }
  __syncthreads();
  {
    float4 a = *(const float4*)(enc_b2+c0);
    for (int k=0;k<128;k+=4){
      const float4 hv = *(const float4*)&s_h[n*132+k];
      a = fma4(a, hv.x, *(const float4*)(enc_w2 + (k+0)*128 + c0));
      a = fma4(a, hv.y, *(const float4*)(enc_w2 + (k+1)*128 + c0));
      a = fma4(a, hv.z, *(const float4*)(enc_w2 + (k+2)*128 + c0));
      a = fma4(a, hv.w, *(const float4*)(enc_w2 + (k+3)*128 + c0));
    }
    a = relu4(a);
    const uint4 p = pack4(a);
    const int i = g*8 + n;
    uint_t* xp = xpk + (size_t)(s*2 + (i>>4))*2048 + (c0>>5)*512 + (i&15)*32 + (c0&31);
    *(uint4*)xp = p;
    if (i == s_ai){
      uint_t* xc = xcatpk + (size_t)(s>>4)*18432 + (c0>>5)*512 + (s&15)*32 + (c0&31);
      *(uint4*)xc = p;
    }
  }
}

// =============== K2: pa1 (blocks 0..511) + wl2/qw1/vw1 converts (512..1343), 512 threads ===============
__global__ __launch_bounds__(512) void pa1_kernel(
    const uint_t* __restrict__ xpk,
    const ushort_t* __restrict__ wl1Thi, const ushort_t* __restrict__ wl1Tlo,
    const ushort_t* __restrict__ wr1Thi, const ushort_t* __restrict__ wr1Tlo,
    const float* __restrict__ att, const float* __restrict__ bias,
    const unsigned* __restrict__ adjw, const int* __restrict__ aiw,
    const float* __restrict__ wl2, const float* __restrict__ q_w1, const float* __restrict__ v_w1,
    ushort_t* __restrict__ wl2Thi, ushort_t* __restrict__ wl2Tlo,
    ushort_t* __restrict__ qw1Thi, ushort_t* __restrict__ qw1Tlo,
    ushort_t* __restrict__ vw1Thi, ushort_t* __restrict__ vw1Tlo,
    uint_t* __restrict__ x2pk, uint_t* __restrict__ xcatpk)
{
  __shared__ __align__(16) float s_gl[32*132];
  __shared__ __align__(16) float s_glB[32*132];
  __shared__ __align__(16) float s_gr[32*132];
  __shared__ __align__(16) float s_grB[32*132];
  __shared__ __align__(16) float s_att[128];
  __shared__ __align__(16) float s_b[128];
  __shared__ float s_lg[32*33];
  __shared__ unsigned s_adj[32];
  const int t = threadIdx.x, bid = blockIdx.x;

  if (bid >= 512){
    const int cw = bid - 512;
    const float* in; ushort_t* ohi; ushort_t* olo; int K, N, tt;
    if (cw < 256)      { in=wl2;  ohi=wl2Thi; olo=wl2Tlo; K=512;  N=512; tt=cw; }
    else if (cw < 544) { in=q_w1; ohi=qw1Thi; olo=qw1Tlo; K=1152; N=256; tt=cw-256; }
    else               { in=v_w1; ohi=vw1Thi; olo=vw1Tlo; K=1152; N=256; tt=cw-544; }
    const int ktiles = K>>5;
    const int kt = tt % ktiles, nt = tt / ktiles;
    const int r = t>>5, c = t&31;   // r in [0,16)
    #pragma unroll
    for (int i=0;i<2;i++)
      s_gl[(r+i*16)*33 + c] = in[(size_t)(kt*32 + r + i*16)*N + nt*32 + c];
    __syncthreads();
    #pragma unroll
    for (int i=0;i<2;i++){
      const int nl = r + i*16;
      const int n  = nt*32 + nl;
      const float f = s_gl[c*33 + nl];
      const unsigned hb = bf16rne(f);
      const float hf = __uint_as_float(hb<<16);
      const unsigned lb = bf16rne(f - hf);
      const size_t off = (size_t)(n>>4)*(16*K) + (size_t)kt*512 + (size_t)(n&15)*32 + c;
      ohi[off] = (ushort_t)hb;
      olo[off] = (ushort_t)lb;
    }
    return;
  }

  const int s = bid >> 2, h = bid & 3;
  const int w = t>>6, lane = t&63, m = lane&15, quad = lane>>4;
  const int ww = w&3, khalf = w>>2;

  if (t < 128){ s_att[t] = att[h*128 + t]; s_b[t] = bias[h*128 + t]; }
  if (t >= 224 && t < 256) s_adj[t-224] = adjw[s*32 + (t-224)];
  const int ai = aiw[s];

  const ushort_t* Bhi = (ww<2) ? wl1Thi : wr1Thi;
  const ushort_t* Blo = (ww<2) ? wl1Tlo : wr1Tlo;
  const int nbase = h*8 + (ww&1)*4;
  const int kcb = khalf*2;
  const uint_t* a0p = xpk + (size_t)(s*2+0)*2048 + m*32 + quad*8 + kcb*512;
  const uint_t* a1p = xpk + (size_t)(s*2+1)*2048 + m*32 + quad*8 + kcb*512;
  const ushort_t* bp0 = Bhi + (size_t)(nbase+0)*2048 + m*32 + quad*8 + kcb*512;
  const ushort_t* bp1 = Bhi + (size_t)(nbase+1)*2048 + m*32 + quad*8 + kcb*512;
  const ushort_t* bp2 = Bhi + (size_t)(nbase+2)*2048 + m*32 + quad*8 + kcb*512;
  const ushort_t* bp3 = Bhi + (size_t)(nbase+3)*2048 + m*32 + quad*8 + kcb*512;
  const size_t lod = (size_t)(Blo - Bhi);
  floatx4 acc[2][4];
  #pragma unroll
  for (int i=0;i<2;i++)
    #pragma unroll
    for (int j=0;j<4;j++) acc[i][j] = (floatx4){0.f,0.f,0.f,0.f};

  #pragma unroll
  for (int kc=0; kc<2; kc++){
    const uint4 u00 = *(const uint4*)(a0p + kc*512);
    const uint4 u01 = *(const uint4*)(a0p + kc*512 + 4);
    const uint4 u10 = *(const uint4*)(a1p + kc*512);
    const uint4 u11 = *(const uint4*)(a1p + kc*512 + 4);
    short8 ahi0, alo0, ahi1, alo1;
    UNPACK8(u00,u01,ahi0,alo0)
    UNPACK8(u10,u11,ahi1,alo1)
    const ushort_t* bps[4] = {bp0, bp1, bp2, bp3};
    #pragma unroll
    for (int nt=0; nt<4; nt++){
      const short8 bh = *(const short8*)(bps[nt] + kc*512);
      const short8 bl = *(const short8*)(bps[nt] + kc*512 + lod);
      acc[0][nt] = __builtin_amdgcn_mfma_f32_16x16x32_bf16(ahi0, bh, acc[0][nt], 0,0,0);
      acc[0][nt] = __builtin_amdgcn_mfma_f32_16x16x32_bf16(ahi0, bl, acc[0][nt], 0,0,0);
      acc[0][nt] = __builtin_amdgcn_mfma_f32_16x16x32_bf16(alo0, bh, acc[0][nt], 0,0,0);
      acc[1][nt] = __builtin_amdgcn_mfma_f32_16x16x32_bf16(ahi1, bh, acc[1][nt], 0,0,0);
      acc[1][nt] = __builtin_amdgcn_mfma_f32_16x16x32_bf16(ahi1, bl, acc[1][nt], 0,0,0);
      acc[1][nt] = __builtin_amdgcn_mfma_f32_16x16x32_bf16(alo1, bh, acc[1][nt], 0,0,0);
    }
  }
  {
    float* dst = (ww<2) ? (khalf ? s_glB : s_gl) : (khalf ? s_grB : s_gr);
    const int colbase = (ww&1)*64;
    #pragma unroll
    for (int nt=0; nt<4; nt++){
      const int col = colbase + nt*16 + m;
      #pragma unroll
      for (int r=0;r<4;r++){
        dst[(quad*4+r)*132 + col]      = acc[0][nt][r];
        dst[(16+quad*4+r)*132 + col]   = acc[1][nt][r];
      }
    }
  }
  __syncthreads();
  for (int e=t; e<32*132; e+=512){
    s_gl[e] += s_glB[e];
    s_gr[e] += s_grB[e];
  }
  __syncthreads();

  // logits
  {
    const int i = t>>4, jb = t&15;
    float lacc[2] = {0.f,0.f};
    for (int c=0;c<128;c+=4){
      const float4 g = *(const float4*)&s_gr[i*132+c];
      const float4 a = *(const float4*)&s_att[c];
      #pragma unroll
      for (int mm=0;mm<2;mm++){
        const float4 gj = *(const float4*)&s_gl[(jb+16*mm)*132 + c];
        float ex = g.x+gj.x; ex = fmaxf(ex, 0.2f*ex);
        float ey = g.y+gj.y; ey = fmaxf(ey, 0.2f*ey);
        float ez = g.z+gj.z; ez = fmaxf(ez, 0.2f*ez);
        float ew = g.w+gj.w; ew = fmaxf(ew, 0.2f*ew);
        lacc[mm] += ex*a.x + ey*a.y + ez*a.z + ew*a.w;
      }
    }
    s_lg[i*33 + jb]      = lacc[0];
    s_lg[i*33 + jb + 16] = lacc[1];
  }
  __syncthreads();

  // masked softmax
  #pragma unroll
  for (int rnd=0; rnd<2; rnd++){
    const int i = rnd*16 + (t>>5), j = t&31;
    const float lg = s_lg[i*33+j];
    const bool ok = (s_adj[i]>>j)&1u;
    float v = ok ? lg : -3.0e38f;
    #pragma unroll
    for (int d_=16; d_; d_>>=1) v = fmaxf(v, __shfl_xor(v, d_, 32));
    const float e = ok ? __expf(lg - v) : 0.f;
    float sum = e;
    #pragma unroll
    for (int d_=16; d_; d_>>=1) sum += __shfl_xor(sum, d_, 32);
    s_lg[i*33+j] = e / sum;
  }
  __syncthreads();

  // aggregate -> packed x2 + tap
  {
    const int i = t>>4, c0 = (t&15)*8;
    float4 o0 = make_float4(0.f,0.f,0.f,0.f), o1 = o0;
    for (int j=0;j<32;j++){
      const float al = s_lg[i*33+j];
      o0 = fma4(o0, al, *(const float4*)&s_gl[j*132 + c0]);
      o1 = fma4(o1, al, *(const float4*)&s_gl[j*132 + c0 + 4]);
    }
    const float4 b0 = *(const float4*)&s_b[c0];
    const float4 b1 = *(const float4*)&s_b[c0+4];
    o0 = relu4(make_float4(o0.x+b0.x, o0.y+b0.y, o0.z+b0.z, o0.w+b0.w));
    o1 = relu4(make_float4(o1.x+b1.x, o1.y+b1.y, o1.z+b1.z, o1.w+b1.w));
    const uint4 p0 = pack4(o0), p1 = pack4(o1);
    const int kb = h*128 + c0;
    uint_t* xp = x2pk + (size_t)(s*2 + (i>>4))*8192 + (kb>>5)*512 + (i&15)*32 + (kb&31);
    *(uint4*)&xp[0] = p0;
    *(uint4*)&xp[4] = p1;
    if (i == ai){
      const int kk = 128 + kb;
      uint_t* tp = xcatpk + (size_t)(s>>4)*18432 + (kk>>5)*512 + (s&15)*32 + (kk&31);
      *(uint4*)&tp[0] = p0;
      *(uint4*)&tp[4] = p1;
    }
  }
}

// =============== K3: pa2 (blocks 0..511) + heads-GEMM ks 0..2 (512..535), 512 threads ===============
__global__ __launch_bounds__(512) void pa2_kernel(
    const uint_t* __restrict__ x2pk,
    const ushort_t* __restrict__ wl2Thi, const ushort_t* __restrict__ wl2Tlo,
    const float* __restrict__ wr2f,
    const float* __restrict__ att2, const float* __restrict__ bias2,
    const unsigned* __restrict__ adjw, const int* __restrict__ aiw,
    const ushort_t* __restrict__ qw1Thi, const ushort_t* __restrict__ qw1Tlo,
    const ushort_t* __restrict__ vw1Thi, const ushort_t* __restrict__ vw1Tlo,
    float* __restrict__ hpart,
    uint_t* __restrict__ xcatpk)
{
  const int t = threadIdx.x, bid = blockIdx.x;
  if (bid >= 512){
    // heads partials for K rows 0..576 (x1/x2 region of xcat — already final)
    const int hk = bid - 512;
    hgemm_body(xcatpk, qw1Thi, qw1Tlo, vw1Thi, vw1Tlo, hpart, hk>>3, hk&7, t);
    return;
  }
  __shared__ __align__(16) float s_gl[32*132];
  __shared__ __align__(16) float s_glB[32*132];
  __shared__ __align__(16) float s_xt[512];
  __shared__ __align__(16) float s_p2[4*128];
  __shared__ __align__(16) float s_at[128];
  __shared__ __align__(16) float s_bb[128];
  __shared__ float s_lg[32];
  __shared__ float s_al[32];
  const int s = bid >> 2, h = bid & 3;
  const int w = t>>6, lane = t&63, m = lane&15, quad = lane>>4;
  const int ww = w&3, khalf = w>>2;
  const int ai = aiw[s];
  const unsigned arow = adjw[s*32+ai];

  {
    const int kk = 128 + t;
    s_xt[t] = unpk(xcatpk[(size_t)(s>>4)*18432 + (kk>>5)*512 + (s&15)*32 + (kk&31)]);
  }
  if (t < 128){ s_at[t] = att2[h*128+t]; s_bb[t] = bias2[h*128+t]; }
  __syncthreads();

  {
    const int c = t&127, q4 = t>>7;
    const float* wp = wr2f + (size_t)(q4*128)*512 + h*128 + c;
    float ga = 0.f;
    #pragma unroll 8
    for (int k=0;k<128;k++) ga += s_xt[q4*128 + k] * wp[(size_t)k*512];
    s_p2[q4*128 + c] = ga;
  }

  const int kcb = khalf*8;
  const uint_t* a0p = x2pk + (size_t)(s*2+0)*8192 + m*32 + quad*8 + kcb*512;
  const uint_t* a1p = x2pk + (size_t)(s*2+1)*8192 + m*32 + quad*8 + kcb*512;
  const ushort_t* bq0 = wl2Thi + (size_t)(h*8 + ww*2+0)*8192 + m*32 + quad*8 + kcb*512;
  const ushort_t* bq1 = wl2Thi + (size_t)(h*8 + ww*2+1)*8192 + m*32 + quad*8 + kcb*512;
  const size_t lod = (size_t)(wl2Tlo - wl2Thi);
  floatx4 acc[2][2];
  #pragma unroll
  for (int i=0;i<2;i++){ acc[i][0] = (floatx4){0.f,0.f,0.f,0.f}; acc[i][1] = acc[i][0]; }
  #pragma unroll 4
  for (int kc=0; kc<8; kc++){
    const uint4 u00 = *(const uint4*)(a0p + kc*512);
    const uint4 u01 = *(const uint4*)(a0p + kc*512 + 4);
    const uint4 u10 = *(const uint4*)(a1p + kc*512);
    const uint4 u11 = *(const uint4*)(a1p + kc*512 + 4);
    short8 ahi0, alo0, ahi1, alo1;
    UNPACK8(u00,u01,ahi0,alo0)
    UNPACK8(u10,u11,ahi1,alo1)
    {
      const short8 bh = *(const short8*)(bq0 + kc*512);
      const short8 bl = *(const short8*)(bq0 + kc*512 + lod);
      acc[0][0] = __builtin_amdgcn_mfma_f32_16x16x32_bf16(ahi0, bh, acc[0][0], 0,0,0);
      acc[0][0] = __builtin_amdgcn_mfma_f32_16x16x32_bf16(ahi0, bl, acc[0][0], 0,0,0);
      acc[0][0] = __builtin_amdgcn_mfma_f32_16x16x32_bf16(alo0, bh, acc[0][0], 0,0,0);
      acc[1][0] = __builtin_amdgcn_mfma_f32_16x16x32_bf16(ahi1, bh, acc[1][0], 0,0,0);
      acc[1][0] = __builtin_amdgcn_mfma_f32_16x16x32_bf16(ahi1, bl, acc[1][0], 0,0,0);
      acc[1][0] = __builtin_amdgcn_mfma_f32_16x16x32_bf16(alo1, bh, acc[1][0], 0,0,0);
    }
    {
      const short8 bh = *(const short8*)(bq1 + kc*512);
      const short8 bl = *(const short8*)(bq1 + kc*512 + lod);
      acc[0][1] = __builtin_amdgcn_mfma_f32_16x16x32_bf16(ahi0, bh, acc[0][1], 0,0,0);
      acc[0][1] = __builtin_amdgcn_mfma_f32_16x16x32_bf16(ahi0, bl, acc[0][1], 0,0,0);
      acc[0][1] = __builtin_amdgcn_mfma_f32_16x16x32_bf16(alo0, bh, acc[0][1], 0,0,0);
      acc[1][1] = __builtin_amdgcn_mfma_f32_16x16x32_bf16(ahi1, bh, acc[1][1], 0,0,0);
      acc[1][1] = __builtin_amdgcn_mfma_f32_16x16x32_bf16(ahi1, bl, acc[1][1], 0,0,0);
      acc[1][1] = __builtin_amdgcn_mfma_f32_16x16x32_bf16(alo1, bh, acc[1][1], 0,0,0);
    }
  }
  {
    float* dst = khalf ? s_glB : s_gl;
    const int colbase = ww*32;
    #pragma unroll
    for (int nt=0; nt<2; nt++){
      const int col = colbase + nt*16 + m;
      #pragma unroll
      for (int r=0;r<4;r++){
        dst[(quad*4+r)*132 + col]    = acc[0][nt][r];
        dst[(16+quad*4+r)*132 + col] = acc[1][nt][r];
      }
    }
  }
  __syncthreads();
  for (int e=t; e<32*132; e+=512) s_gl[e] += s_glB[e];
  if (t < 128) s_p2[t] = s_p2[t] + s_p2[128+t] + s_p2[256+t] + s_p2[384+t];
  __syncthreads();

  if (t < 256){
    const int j = t>>3, pq = t&7;
    float sum = 0.f;
    #pragma unroll
    for (int q=0;q<4;q++){
      const int c = pq*16 + q*4;
      const float4 g = *(const float4*)&s_gl[j*132 + c];
      const float4 r = *(const float4*)&s_p2[c];
      const float4 a = *(const float4*)&s_at[c];
      float e0 = r.x+g.x; e0 = fmaxf(e0, 0.2f*e0);
      float e1 = r.y+g.y; e1 = fmaxf(e1, 0.2f*e1);
      float e2 = r.z+g.z; e2 = fmaxf(e2, 0.2f*e2);
      float e3 = r.w+g.w; e3 = fmaxf(e3, 0.2f*e3);
      sum += e0*a.x + e1*a.y + e2*a.z + e3*a.w;
    }
    sum += __shfl_xor(sum,1,64);
    sum += __shfl_xor(sum,2,64);
    sum += __shfl_xor(sum,4,64);
    if (pq==0) s_lg[j] = sum;
  }
  __syncthreads();
  if (t < 32){
    const float lg = s_lg[t];
    const bool ok = (arow>>t)&1u;
    float v = ok ? lg : -3.0e38f;
    #pragma unroll
    for (int d_=16; d_; d_>>=1) v = fmaxf(v, __shfl_xor(v, d_, 32));
    const float e = ok ? __expf(lg - v) : 0.f;
    float sm = e;
    #pragma unroll
    for (int d_=16; d_; d_>>=1) sm += __shfl_xor(sm, d_, 32);
    s_al[t] = e / sm;
  }
  __syncthreads();
  if (t < 128){
    float acc2 = 0.f;
    #pragma unroll 8
    for (int j=0;j<32;j++) acc2 += s_al[j] * s_gl[j*132 + t];
    const int kk = 640 + h*128 + t;
    xcatpk[(size_t)(s>>4)*18432 + (kk>>5)*512 + (s&15)*32 + (kk&31)]
        = packbf(fmaxf(acc2 + s_bb[t], 0.f));
  }
}

// =============== K4: heads-GEMM ks 3..5 (24 blocks, 512 threads) ===============
__global__ __launch_bounds__(512) void hgemm_kernel(
    const uint_t* __restrict__ xcatpk,
    const ushort_t* __restrict__ qw1Thi, const ushort_t* __restrict__ qw1Tlo,
    const ushort_t* __restrict__ vw1Thi, const ushort_t* __restrict__ vw1Tlo,
    float* __restrict__ hpart)
{
  const int t = threadIdx.x, bid = blockIdx.x;
  hgemm_body(xcatpk, qw1Thi, qw1Tlo, vw1Thi, vw1Tlo, hpart, 3 + (bid>>3), bid&7, t);
}

// =============== K5: heads epilogue (sum 6 partials) + final combine ===============
__global__ __launch_bounds__(256) void hepi_kernel(
    const float* __restrict__ hpart,
    const float* __restrict__ q_b1, const float* __restrict__ q_w2, const float* __restrict__ q_b2,
    const float* __restrict__ v_b1, const float* __restrict__ v_w2, const float* __restrict__ v_b2,
    float* __restrict__ out)
{
  __shared__ float s_p[4*6];
  const int t = threadIdx.x, s = blockIdx.x;
  float hq = q_b1[t], hv = v_b1[t];
  #pragma unroll
  for (int ks=0; ks<6; ks++){
    hq += hpart[(size_t)ks*65536 + (size_t)s*512 + t];
    hv += hpart[(size_t)ks*65536 + (size_t)s*512 + 256 + t];
  }
  hq = fmaxf(hq, 0.f);
  hv = fmaxf(hv, 0.f);
  float p[6];
  #pragma unroll
  for (int o=0;o<5;o++) p[o] = hq * q_w2[t*5+o];
  p[5] = hv * v_w2[t];
  #pragma unroll
  for (int d_=32; d_; d_>>=1){
    #pragma unroll
    for (int o=0;o<6;o++) p[o] += __shfl_xor(p[o], d_, 64);
  }
  const int w = t>>6, lane = t&63;
  if (lane==0){
    #pragma unroll
    for (int o=0;o<6;o++) s_p[w*6+o] = p[o];
  }
  __syncthreads();
  if (t < 6) s_p[t] = s_p[t] + s_p[6+t] + s_p[12+t] + s_p[18+t];
  __syncthreads();
  if (t < 5){
    const float q0 = s_p[0]+q_b2[0], q1 = s_p[1]+q_b2[1], q2 = s_p[2]+q_b2[2],
                q3 = s_p[3]+q_b2[3], q4 = s_p[4]+q_b2[4];
    const float mean = (q0+q1+q2+q3+q4) / 5.0f;
    const float v = s_p[5] + v_b2[0];
    const float qt = (t==0?q0:t==1?q1:t==2?q2:t==3?q3:q4);
    out[s*5+t] = qt - mean + v;
  }
}

extern "C" void kernel_launch(void* const* d_in, const int* in_sizes, int n_in,
                              void* d_out, int out_size, void* d_ws, size_t ws_size,
                              hipStream_t stream) {
  (void)n_in; (void)out_size; (void)ws_size;
  const float* obs    = (const float*)d_in[0];
  const float* enc_w1 = (const float*)d_in[1];
  const float* enc_b1 = (const float*)d_in[2];
  const float* enc_w2 = (const float*)d_in[3];
  const float* enc_b2 = (const float*)d_in[4];
  const float* wl1    = (const float*)d_in[5];
  const float* wr1    = (const float*)d_in[6];
  const float* att1   = (const float*)d_in[7];
  const float* bias1  = (const float*)d_in[8];
  const float* wl2    = (const float*)d_in[9];
  const float* wr2    = (const float*)d_in[10];
  const float* att2   = (const float*)d_in[11];
  const float* bias2  = (const float*)d_in[12];
  const float* q_w1   = (const float*)d_in[13];
  const float* q_b1   = (const float*)d_in[14];
  const float* q_w2   = (const float*)d_in[15];
  const float* q_b2   = (const float*)d_in[16];
  const float* v_w1   = (const float*)d_in[17];
  const float* v_b1   = (const float*)d_in[18];
  const float* v_w2   = (const float*)d_in[19];
  const float* v_b2   = (const float*)d_in[20];

  char* ws = (char*)d_ws;
  uint_t*   x_pk    = (uint_t*)  (ws + 0);
  uint_t*   xcat_pk = (uint_t*)  (ws + 2097152);
  unsigned* adjw    = (unsigned*)(ws + 2686976);
  int*      aiw     = (int*)     (ws + 2703360);
  uint_t*   x2_pk   = (uint_t*)  (ws + 2703872);
  ushort_t* wl1Thi  = (ushort_t*)(ws + 11092480);
  ushort_t* wl1Tlo  = (ushort_t*)(ws + 11223552);
  ushort_t* wr1Thi  = (ushort_t*)(ws + 11354624);
  ushort_t* wr1Tlo  = (ushort_t*)(ws + 11485696);
  ushort_t* wl2Thi  = (ushort_t*)(ws + 11616768);
  ushort_t* wl2Tlo  = (ushort_t*)(ws + 12141056);
  ushort_t* qw1Thi  = (ushort_t*)(ws + 12665344);
  ushort_t* qw1Tlo  = (ushort_t*)(ws + 13255168);
  ushort_t* vw1Thi  = (ushort_t*)(ws + 13844992);
  ushort_t* vw1Tlo  = (ushort_t*)(ws + 14434816);
  float*    hpart   = (float*)   (ws + 15024640);   // 6*128*512*4 = 1,572,864

  const int bs = in_sizes[0] / 577;   // 128

  // K1: enc (512 blocks) + wl1/wr1 converts (128 blocks)
  prep_kernel<<<512 + 128, 256, 0, stream>>>(obs, enc_w1, enc_b1, enc_w2, enc_b2,
      wl1, wr1, wl1Thi, wl1Tlo, wr1Thi, wr1Tlo,
      x_pk, xcat_pk, adjw, aiw);

  // K2: pa1 (512 blocks) + wl2/qw1/vw1 converts (832 blocks)
  pa1_kernel<<<512 + 832, 512, 0, stream>>>(x_pk, wl1Thi, wl1Tlo, wr1Thi, wr1Tlo,
      att1, bias1, adjw, aiw,
      wl2, q_w1, v_w1, wl2Thi, wl2Tlo, qw1Thi, qw1Tlo, vw1Thi, vw1Tlo,
      x2_pk, xcat_pk);

  // K3: pa2 (512 blocks) + heads partials ks 0..2 (24 blocks, K rows 0..576 < 640)
  pa2_kernel<<<512 + 24, 512, 0, stream>>>(x2_pk, wl2Thi, wl2Tlo, wr2,
      att2, bias2, adjw, aiw,
      qw1Thi, qw1Tlo, vw1Thi, vw1Tlo, hpart, xcat_pk);

  // K4: heads partials ks 3..5 (need x3 from pa2)
  hgemm_kernel<<<24, 512, 0, stream>>>(xcat_pk, qw1Thi, qw1Tlo, vw1Thi, vw1Tlo, hpart);

  // K5: epilogue
  hepi_kernel<<<bs, 256, 0, stream>>>(hpart, q_b1, q_w2, q_b2, v_b1, v_w2, v_b2,
                                      (float*)d_out);
}

// Round 14
// 175.565 us; speedup vs baseline: 1.2063x; 1.0323x over previous
//
#include <hip/hip_runtime.h>
#include <hip/hip_bf16.h>

typedef unsigned int uint_t;
typedef unsigned short ushort_t;
typedef __attribute__((ext_vector_type(8))) short short8;
typedef __attribute__((ext_vector_type(4))) float floatx4;

__device__ __forceinline__ float4 fma4(float4 a, float s, float4 w){
  a.x += s*w.x; a.y += s*w.y; a.z += s*w.z; a.w += s*w.w; return a;
}
__device__ __forceinline__ float4 relu4(float4 a){
  return make_float4(fmaxf(a.x,0.f),fmaxf(a.y,0.f),fmaxf(a.z,0.f),fmaxf(a.w,0.f));
}
__device__ __forceinline__ unsigned bf16rne(float f){
  unsigned u = __float_as_uint(f);
  return (u + 0x7fffu + ((u>>16)&1u)) >> 16;
}
__device__ __forceinline__ uint_t packbf(float f){
  unsigned hb = bf16rne(f);
  float hf = __uint_as_float(hb<<16);
  unsigned lb = bf16rne(f - hf);
  return (hb<<16) | lb;
}
__device__ __forceinline__ uint4 pack4(float4 v){
  uint4 u; u.x=packbf(v.x); u.y=packbf(v.y); u.z=packbf(v.z); u.w=packbf(v.w); return u;
}
__device__ __forceinline__ float unpk(uint_t u){
  return __uint_as_float(u & 0xffff0000u) + __uint_as_float(u<<16);
}
#define UNPACK8(u0,u1,hi,lo) \
  hi[0]=(short)(u0.x>>16); lo[0]=(short)u0.x; \
  hi[1]=(short)(u0.y>>16); lo[1]=(short)u0.y; \
  hi[2]=(short)(u0.z>>16); lo[2]=(short)u0.z; \
  hi[3]=(short)(u0.w>>16); lo[3]=(short)u0.w; \
  hi[4]=(short)(u1.x>>16); lo[4]=(short)u1.x; \
  hi[5]=(short)(u1.y>>16); lo[5]=(short)u1.y; \
  hi[6]=(short)(u1.z>>16); lo[6]=(short)u1.z; \
  hi[7]=(short)(u1.w>>16); lo[7]=(short)u1.w;

// Fragment-order offset: off(n,k) = (n>>4)*16*K + (k>>5)*512 + (n&15)*32 + (k&31)

// heads GEMM K-split body: job (ks in 0..3, ct in 0..7), 512 threads (8 waves = 8 row-blocks).
// Partial [128 x 64cols] over kc = ks*5 .. ks*5+4 (k rows 0..640 = x1+x2) -> hpart[ks].
__device__ __forceinline__ void hgemm_body(
    const uint_t* __restrict__ xcatpk,
    const ushort_t* __restrict__ qw1Thi, const ushort_t* __restrict__ qw1Tlo,
    const ushort_t* __restrict__ vw1Thi, const ushort_t* __restrict__ vw1Tlo,
    float* __restrict__ part, int ks, int ct, int t)
{
  const int w = t>>6, lane = t&63, m = lane&15, quad = lane>>4;
  const ushort_t* Bhi = (ct<4) ? qw1Thi : vw1Thi;
  const int cbl = (ct<4) ? ct*64 : (ct-4)*64;
  const int cbg = (ct<4) ? ct*64 : 256 + (ct-4)*64;
  const uint_t* ap = xcatpk + (size_t)w*18432 + m*32 + quad*8 + (size_t)(ks*5)*512;
  const ushort_t* bp0 = Bhi + (size_t)((cbl>>4)+0)*18432 + m*32 + quad*8 + (size_t)(ks*5)*512;
  const ushort_t* bp1 = Bhi + (size_t)((cbl>>4)+1)*18432 + m*32 + quad*8 + (size_t)(ks*5)*512;
  const ushort_t* bp2 = Bhi + (size_t)((cbl>>4)+2)*18432 + m*32 + quad*8 + (size_t)(ks*5)*512;
  const ushort_t* bp3 = Bhi + (size_t)((cbl>>4)+3)*18432 + m*32 + quad*8 + (size_t)(ks*5)*512;
  const size_t lod = (size_t)(qw1Tlo - qw1Thi);   // identical gap for q and v
  floatx4 acc[4];
  #pragma unroll
  for (int i=0;i<4;i++) acc[i] = (floatx4){0.f,0.f,0.f,0.f};
  #pragma unroll
  for (int kc=0; kc<5; kc++){
    const uint4 ua0 = *(const uint4*)(ap);
    const uint4 ua1 = *(const uint4*)(ap+4);
    ap += 512;
    short8 ahi, alo;
    UNPACK8(ua0,ua1,ahi,alo)
    const ushort_t* bps[4] = {bp0, bp1, bp2, bp3};
    #pragma unroll
    for (int nt=0; nt<4; nt++){
      const short8 bh = *(const short8*)(bps[nt] + kc*512);
      const short8 bl = *(const short8*)(bps[nt] + kc*512 + lod);
      acc[nt] = __builtin_amdgcn_mfma_f32_16x16x32_bf16(ahi, bh, acc[nt], 0,0,0);
      acc[nt] = __builtin_amdgcn_mfma_f32_16x16x32_bf16(ahi, bl, acc[nt], 0,0,0);
      acc[nt] = __builtin_amdgcn_mfma_f32_16x16x32_bf16(alo, bh, acc[nt], 0,0,0);
    }
  }
  float* pdst = part + (size_t)ks*65536;
  const int crow0 = w*16 + quad*4;
  #pragma unroll
  for (int nt=0; nt<4; nt++){
    const int col = cbg + nt*16 + m;
    #pragma unroll
    for (int r=0;r<4;r++)
      pdst[(size_t)(crow0 + r)*512 + col] = acc[nt][r];
  }
}

// =============== K1: enc (blocks 0..511) + wl1/wr1 convert (512..639) ===============
__global__ __launch_bounds__(256) void prep_kernel(
    const float* __restrict__ obs,
    const float* __restrict__ enc_w1, const float* __restrict__ enc_b1,
    const float* __restrict__ enc_w2, const float* __restrict__ enc_b2,
    const float* __restrict__ wl1, const float* __restrict__ wr1,
    ushort_t* __restrict__ wl1Thi, ushort_t* __restrict__ wl1Tlo,
    ushort_t* __restrict__ wr1Thi, ushort_t* __restrict__ wr1Tlo,
    uint_t* __restrict__ xpk, uint_t* __restrict__ xcatpk,
    unsigned* __restrict__ adjw, int* __restrict__ aiw)
{
  const int t = threadIdx.x, bid = blockIdx.x;
  if (bid >= 512){
    __shared__ float sm[32][33];
    const int cw = bid - 512;
    const float* in; ushort_t* ohi; ushort_t* olo; int tt;
    const int K = 128, N = 512;
    if (cw < 64){ in=wl1; ohi=wl1Thi; olo=wl1Tlo; tt=cw; }
    else        { in=wr1; ohi=wr1Thi; olo=wr1Tlo; tt=cw-64; }
    const int ktiles = K>>5;
    const int kt = tt % ktiles, nt = tt / ktiles;
    const int r = t>>5, c = t&31;
    #pragma unroll
    for (int i=0;i<4;i++)
      sm[r+i*8][c] = in[(size_t)(kt*32 + r + i*8)*N + nt*32 + c];
    __syncthreads();
    #pragma unroll
    for (int i=0;i<4;i++){
      const int nl = r + i*8;
      const int n  = nt*32 + nl;
      const float f = sm[c][nl];
      const unsigned hb = bf16rne(f);
      const float hf = __uint_as_float(hb<<16);
      const unsigned lb = bf16rne(f - hf);
      const size_t off = (size_t)(n>>4)*(16*K) + (size_t)kt*512 + (size_t)(n&15)*32 + c;
      ohi[off] = (ushort_t)hb;
      olo[off] = (ushort_t)lb;
    }
    return;
  }
  __shared__ float s_pos[64];
  __shared__ float s_feats[128];
  __shared__ __align__(16) float s_h[8*132];
  __shared__ int s_ai;
  const int s = bid>>2, g = bid&3;
  const float* ob = obs + s*577;

  if (t==0){
    float a = ob[576];
    a = fminf(fmaxf(a, 0.f), 31.f);
    s_ai = (int)a;
    if (g==0) aiw[s] = (int)a;
  }
  if (t < 128){ const int n=t>>4, f=t&15; s_feats[t] = ob[(g*8+n)*18+2+f]; }
  if (g==0 && t>=128 && t<192){ const int u=t-128; s_pos[u] = ob[(u>>1)*18 + (u&1)]; }
  __syncthreads();

  if (g==0 && t < 32){
    const float px = s_pos[2*t], py = s_pos[2*t+1];
    const float R2 = 0.09f;
    unsigned mm = 0u;
    for (int j=0;j<32;j++){
      const float dx = __fsub_rn(px, s_pos[2*j]), dy = __fsub_rn(py, s_pos[2*j+1]);
      const float d2 = __fadd_rn(__fmul_rn(dx,dx), __fmul_rn(dy,dy));
      if (d2 <= R2 || j==t) mm |= (1u<<j);
    }
    adjw[s*32+t] = mm;
  }

  const int n = t>>5, c0 = (t&31)*4;
  {
    float4 a = *(const float4*)(enc_b1+c0);
    #pragma unroll
    for (int f=0; f<16; f++)
      a = fma4(a, s_feats[n*16+f], *(const float4*)(enc_w1 + f*128 + c0));
    *(float4*)&s_h[n*132+c0] = relu4(a);
  }
  __syncthreads();
  {
    float4 a = *(const float4*)(enc_b2+c0);
    for (int k=0;k<128;k+=4){
      const float4 hv = *(const float4*)&s_h[n*132+k];
      a = fma4(a, hv.x, *(const float4*)(enc_w2 + (k+0)*128 + c0));
      a = fma4(a, hv.y, *(const float4*)(enc_w2 + (k+1)*128 + c0));
      a = fma4(a, hv.z, *(const float4*)(enc_w2 + (k+2)*128 + c0));
      a = fma4(a, hv.w, *(const float4*)(enc_w2 + (k+3)*128 + c0));
    }
    a = relu4(a);
    const uint4 p = pack4(a);
    const int i = g*8 + n;
    uint_t* xp = xpk + (size_t)(s*2 + (i>>4))*2048 + (c0>>5)*512 + (i&15)*32 + (c0&31);
    *(uint4*)xp = p;
    if (i == s_ai){
      uint_t* xc = xcatpk + (size_t)(s>>4)*18432 + (c0>>5)*512 + (s&15)*32 + (c0&31);
      *(uint4*)xc = p;
    }
  }
}

// =============== K2: pa1 (blocks 0..511) + wl2/qw1/vw1 converts (512..1343), 512 threads ===============
__global__ __launch_bounds__(512) void pa1_kernel(
    const uint_t* __restrict__ xpk,
    const ushort_t* __restrict__ wl1Thi, const ushort_t* __restrict__ wl1Tlo,
    const ushort_t* __restrict__ wr1Thi, const ushort_t* __restrict__ wr1Tlo,
    const float* __restrict__ att, const float* __restrict__ bias,
    const unsigned* __restrict__ adjw, const int* __restrict__ aiw,
    const float* __restrict__ wl2, const float* __restrict__ q_w1, const float* __restrict__ v_w1,
    ushort_t* __restrict__ wl2Thi, ushort_t* __restrict__ wl2Tlo,
    ushort_t* __restrict__ qw1Thi, ushort_t* __restrict__ qw1Tlo,
    ushort_t* __restrict__ vw1Thi, ushort_t* __restrict__ vw1Tlo,
    uint_t* __restrict__ x2pk, uint_t* __restrict__ xcatpk)
{
  __shared__ __align__(16) float s_gl[32*132];
  __shared__ __align__(16) float s_glB[32*132];
  __shared__ __align__(16) float s_gr[32*132];
  __shared__ __align__(16) float s_grB[32*132];
  __shared__ __align__(16) float s_att[128];
  __shared__ __align__(16) float s_b[128];
  __shared__ float s_lg[32*33];
  __shared__ unsigned s_adj[32];
  const int t = threadIdx.x, bid = blockIdx.x;

  if (bid >= 512){
    const int cw = bid - 512;
    const float* in; ushort_t* ohi; ushort_t* olo; int K, N, tt;
    if (cw < 256)      { in=wl2;  ohi=wl2Thi; olo=wl2Tlo; K=512;  N=512; tt=cw; }
    else if (cw < 544) { in=q_w1; ohi=qw1Thi; olo=qw1Tlo; K=1152; N=256; tt=cw-256; }
    else               { in=v_w1; ohi=vw1Thi; olo=vw1Tlo; K=1152; N=256; tt=cw-544; }
    const int ktiles = K>>5;
    const int kt = tt % ktiles, nt = tt / ktiles;
    const int r = t>>5, c = t&31;   // r in [0,16)
    #pragma unroll
    for (int i=0;i<2;i++)
      s_gl[(r+i*16)*33 + c] = in[(size_t)(kt*32 + r + i*16)*N + nt*32 + c];
    __syncthreads();
    #pragma unroll
    for (int i=0;i<2;i++){
      const int nl = r + i*16;
      const int n  = nt*32 + nl;
      const float f = s_gl[c*33 + nl];
      const unsigned hb = bf16rne(f);
      const float hf = __uint_as_float(hb<<16);
      const unsigned lb = bf16rne(f - hf);
      const size_t off = (size_t)(n>>4)*(16*K) + (size_t)kt*512 + (size_t)(n&15)*32 + c;
      ohi[off] = (ushort_t)hb;
      olo[off] = (ushort_t)lb;
    }
    return;
  }

  const int s = bid >> 2, h = bid & 3;
  const int w = t>>6, lane = t&63, m = lane&15, quad = lane>>4;
  const int ww = w&3, khalf = w>>2;

  if (t < 128){ s_att[t] = att[h*128 + t]; s_b[t] = bias[h*128 + t]; }
  if (t >= 224 && t < 256) s_adj[t-224] = adjw[s*32 + (t-224)];
  const int ai = aiw[s];

  const ushort_t* Bhi = (ww<2) ? wl1Thi : wr1Thi;
  const ushort_t* Blo = (ww<2) ? wl1Tlo : wr1Tlo;
  const int nbase = h*8 + (ww&1)*4;
  const int kcb = khalf*2;
  const uint_t* a0p = xpk + (size_t)(s*2+0)*2048 + m*32 + quad*8 + kcb*512;
  const uint_t* a1p = xpk + (size_t)(s*2+1)*2048 + m*32 + quad*8 + kcb*512;
  const ushort_t* bp0 = Bhi + (size_t)(nbase+0)*2048 + m*32 + quad*8 + kcb*512;
  const ushort_t* bp1 = Bhi + (size_t)(nbase+1)*2048 + m*32 + quad*8 + kcb*512;
  const ushort_t* bp2 = Bhi + (size_t)(nbase+2)*2048 + m*32 + quad*8 + kcb*512;
  const ushort_t* bp3 = Bhi + (size_t)(nbase+3)*2048 + m*32 + quad*8 + kcb*512;
  const size_t lod = (size_t)(Blo - Bhi);
  floatx4 acc[2][4];
  #pragma unroll
  for (int i=0;i<2;i++)
    #pragma unroll
    for (int j=0;j<4;j++) acc[i][j] = (floatx4){0.f,0.f,0.f,0.f};

  #pragma unroll
  for (int kc=0; kc<2; kc++){
    const uint4 u00 = *(const uint4*)(a0p + kc*512);
    const uint4 u01 = *(const uint4*)(a0p + kc*512 + 4);
    const uint4 u10 = *(const uint4*)(a1p + kc*512);
    const uint4 u11 = *(const uint4*)(a1p + kc*512 + 4);
    short8 ahi0, alo0, ahi1, alo1;
    UNPACK8(u00,u01,ahi0,alo0)
    UNPACK8(u10,u11,ahi1,alo1)
    const ushort_t* bps[4] = {bp0, bp1, bp2, bp3};
    #pragma unroll
    for (int nt=0; nt<4; nt++){
      const short8 bh = *(const short8*)(bps[nt] + kc*512);
      const short8 bl = *(const short8*)(bps[nt] + kc*512 + lod);
      acc[0][nt] = __builtin_amdgcn_mfma_f32_16x16x32_bf16(ahi0, bh, acc[0][nt], 0,0,0);
      acc[0][nt] = __builtin_amdgcn_mfma_f32_16x16x32_bf16(ahi0, bl, acc[0][nt], 0,0,0);
      acc[0][nt] = __builtin_amdgcn_mfma_f32_16x16x32_bf16(alo0, bh, acc[0][nt], 0,0,0);
      acc[1][nt] = __builtin_amdgcn_mfma_f32_16x16x32_bf16(ahi1, bh, acc[1][nt], 0,0,0);
      acc[1][nt] = __builtin_amdgcn_mfma_f32_16x16x32_bf16(ahi1, bl, acc[1][nt], 0,0,0);
      acc[1][nt] = __builtin_amdgcn_mfma_f32_16x16x32_bf16(alo1, bh, acc[1][nt], 0,0,0);
    }
  }
  {
    float* dst = (ww<2) ? (khalf ? s_glB : s_gl) : (khalf ? s_grB : s_gr);
    const int colbase = (ww&1)*64;
    #pragma unroll
    for (int nt=0; nt<4; nt++){
      const int col = colbase + nt*16 + m;
      #pragma unroll
      for (int r=0;r<4;r++){
        dst[(quad*4+r)*132 + col]      = acc[0][nt][r];
        dst[(16+quad*4+r)*132 + col]   = acc[1][nt][r];
      }
    }
  }
  __syncthreads();
  for (int e=t; e<32*132; e+=512){
    s_gl[e] += s_glB[e];
    s_gr[e] += s_grB[e];
  }
  __syncthreads();

  // logits
  {
    const int i = t>>4, jb = t&15;
    float lacc[2] = {0.f,0.f};
    for (int c=0;c<128;c+=4){
      const float4 g = *(const float4*)&s_gr[i*132+c];
      const float4 a = *(const float4*)&s_att[c];
      #pragma unroll
      for (int mm=0;mm<2;mm++){
        const float4 gj = *(const float4*)&s_gl[(jb+16*mm)*132 + c];
        float ex = g.x+gj.x; ex = fmaxf(ex, 0.2f*ex);
        float ey = g.y+gj.y; ey = fmaxf(ey, 0.2f*ey);
        float ez = g.z+gj.z; ez = fmaxf(ez, 0.2f*ez);
        float ew = g.w+gj.w; ew = fmaxf(ew, 0.2f*ew);
        lacc[mm] += ex*a.x + ey*a.y + ez*a.z + ew*a.w;
      }
    }
    s_lg[i*33 + jb]      = lacc[0];
    s_lg[i*33 + jb + 16] = lacc[1];
  }
  __syncthreads();

  // masked softmax
  #pragma unroll
  for (int rnd=0; rnd<2; rnd++){
    const int i = rnd*16 + (t>>5), j = t&31;
    const float lg = s_lg[i*33+j];
    const bool ok = (s_adj[i]>>j)&1u;
    float v = ok ? lg : -3.0e38f;
    #pragma unroll
    for (int d_=16; d_; d_>>=1) v = fmaxf(v, __shfl_xor(v, d_, 32));
    const float e = ok ? __expf(lg - v) : 0.f;
    float sum = e;
    #pragma unroll
    for (int d_=16; d_; d_>>=1) sum += __shfl_xor(sum, d_, 32);
    s_lg[i*33+j] = e / sum;
  }
  __syncthreads();

  // aggregate -> packed x2 + tap
  {
    const int i = t>>4, c0 = (t&15)*8;
    float4 o0 = make_float4(0.f,0.f,0.f,0.f), o1 = o0;
    for (int j=0;j<32;j++){
      const float al = s_lg[i*33+j];
      o0 = fma4(o0, al, *(const float4*)&s_gl[j*132 + c0]);
      o1 = fma4(o1, al, *(const float4*)&s_gl[j*132 + c0 + 4]);
    }
    const float4 b0 = *(const float4*)&s_b[c0];
    const float4 b1 = *(const float4*)&s_b[c0+4];
    o0 = relu4(make_float4(o0.x+b0.x, o0.y+b0.y, o0.z+b0.z, o0.w+b0.w));
    o1 = relu4(make_float4(o1.x+b1.x, o1.y+b1.y, o1.z+b1.z, o1.w+b1.w));
    const uint4 p0 = pack4(o0), p1 = pack4(o1);
    const int kb = h*128 + c0;
    uint_t* xp = x2pk + (size_t)(s*2 + (i>>4))*8192 + (kb>>5)*512 + (i&15)*32 + (kb&31);
    *(uint4*)&xp[0] = p0;
    *(uint4*)&xp[4] = p1;
    if (i == ai){
      const int kk = 128 + kb;
      uint_t* tp = xcatpk + (size_t)(s>>4)*18432 + (kk>>5)*512 + (s&15)*32 + (kk&31);
      *(uint4*)&tp[0] = p0;
      *(uint4*)&tp[4] = p1;
    }
  }
}

// =============== K3: pa2 (0..511) + heads-GEMM x1/x2 partials ks0..3 (512..543) ===============
__global__ __launch_bounds__(512) void pa2_kernel(
    const uint_t* __restrict__ x2pk,
    const ushort_t* __restrict__ wl2Thi, const ushort_t* __restrict__ wl2Tlo,
    const float* __restrict__ wr2f,
    const float* __restrict__ att2, const float* __restrict__ bias2,
    const unsigned* __restrict__ adjw, const int* __restrict__ aiw,
    const ushort_t* __restrict__ qw1Thi, const ushort_t* __restrict__ qw1Tlo,
    const ushort_t* __restrict__ vw1Thi, const ushort_t* __restrict__ vw1Tlo,
    const float* __restrict__ q_w1f, const float* __restrict__ v_w1f,
    float* __restrict__ hpart, float* __restrict__ hp3,
    uint_t* __restrict__ xcatpk)
{
  const int t = threadIdx.x, bid = blockIdx.x;
  if (bid >= 512){
    const int hk = bid - 512;     // 0..31: ks = hk>>3 (0..3), ct = hk&7
    hgemm_body(xcatpk, qw1Thi, qw1Tlo, vw1Thi, vw1Tlo, hpart, hk>>3, hk&7, t);
    return;
  }
  __shared__ __align__(16) float s_gl[32*132];
  __shared__ __align__(16) float s_glB[32*132];
  __shared__ __align__(16) float s_xt[512];
  __shared__ __align__(16) float s_p2[4*128];
  __shared__ __align__(16) float s_at[128];
  __shared__ __align__(16) float s_bb[128];
  __shared__ float s_lg[32];
  __shared__ float s_al[32];
  const int s = bid >> 2, h = bid & 3;
  const int w = t>>6, lane = t&63, m = lane&15, quad = lane>>4;
  const int ww = w&3, khalf = w>>2;
  const int ai = aiw[s];
  const unsigned arow = adjw[s*32+ai];

  {
    const int kk = 128 + t;
    s_xt[t] = unpk(xcatpk[(size_t)(s>>4)*18432 + (kk>>5)*512 + (s&15)*32 + (kk&31)]);
  }
  if (t < 128){ s_at[t] = att2[h*128+t]; s_bb[t] = bias2[h*128+t]; }
  __syncthreads();

  // grt partial (4-way K split)
  {
    const int c = t&127, q4 = t>>7;
    const float* wp = wr2f + (size_t)(q4*128)*512 + h*128 + c;
    float ga = 0.f;
    #pragma unroll 8
    for (int k=0;k<128;k++) ga += s_xt[q4*128 + k] * wp[(size_t)k*512];
    s_p2[q4*128 + c] = ga;
  }

  const int kcb = khalf*8;
  const uint_t* a0p = x2pk + (size_t)(s*2+0)*8192 + m*32 + quad*8 + kcb*512;
  const uint_t* a1p = x2pk + (size_t)(s*2+1)*8192 + m*32 + quad*8 + kcb*512;
  const ushort_t* bq0 = wl2Thi + (size_t)(h*8 + ww*2+0)*8192 + m*32 + quad*8 + kcb*512;
  const ushort_t* bq1 = wl2Thi + (size_t)(h*8 + ww*2+1)*8192 + m*32 + quad*8 + kcb*512;
  const size_t lod = (size_t)(wl2Tlo - wl2Thi);
  floatx4 acc[2][2];
  #pragma unroll
  for (int i=0;i<2;i++){ acc[i][0] = (floatx4){0.f,0.f,0.f,0.f}; acc[i][1] = acc[i][0]; }
  #pragma unroll 4
  for (int kc=0; kc<8; kc++){
    const uint4 u00 = *(const uint4*)(a0p + kc*512);
    const uint4 u01 = *(const uint4*)(a0p + kc*512 + 4);
    const uint4 u10 = *(const uint4*)(a1p + kc*512);
    const uint4 u11 = *(const uint4*)(a1p + kc*512 + 4);
    short8 ahi0, alo0, ahi1, alo1;
    UNPACK8(u00,u01,ahi0,alo0)
    UNPACK8(u10,u11,ahi1,alo1)
    {
      const short8 bh = *(const short8*)(bq0 + kc*512);
      const short8 bl = *(const short8*)(bq0 + kc*512 + lod);
      acc[0][0] = __builtin_amdgcn_mfma_f32_16x16x32_bf16(ahi0, bh, acc[0][0], 0,0,0);
      acc[0][0] = __builtin_amdgcn_mfma_f32_16x16x32_bf16(ahi0, bl, acc[0][0], 0,0,0);
      acc[0][0] = __builtin_amdgcn_mfma_f32_16x16x32_bf16(alo0, bh, acc[0][0], 0,0,0);
      acc[1][0] = __builtin_amdgcn_mfma_f32_16x16x32_bf16(ahi1, bh, acc[1][0], 0,0,0);
      acc[1][0] = __builtin_amdgcn_mfma_f32_16x16x32_bf16(ahi1, bl, acc[1][0], 0,0,0);
      acc[1][0] = __builtin_amdgcn_mfma_f32_16x16x32_bf16(alo1, bh, acc[1][0], 0,0,0);
    }
    {
      const short8 bh = *(const short8*)(bq1 + kc*512);
      const short8 bl = *(const short8*)(bq1 + kc*512 + lod);
      acc[0][1] = __builtin_amdgcn_mfma_f32_16x16x32_bf16(ahi0, bh, acc[0][1], 0,0,0);
      acc[0][1] = __builtin_amdgcn_mfma_f32_16x16x32_bf16(ahi0, bl, acc[0][1], 0,0,0);
      acc[0][1] = __builtin_amdgcn_mfma_f32_16x16x32_bf16(alo0, bh, acc[0][1], 0,0,0);
      acc[1][1] = __builtin_amdgcn_mfma_f32_16x16x32_bf16(ahi1, bh, acc[1][1], 0,0,0);
      acc[1][1] = __builtin_amdgcn_mfma_f32_16x16x32_bf16(ahi1, bl, acc[1][1], 0,0,0);
      acc[1][1] = __builtin_amdgcn_mfma_f32_16x16x32_bf16(alo1, bh, acc[1][1], 0,0,0);
    }
  }
  {
    float* dst = khalf ? s_glB : s_gl;
    const int colbase = ww*32;
    #pragma unroll
    for (int nt=0; nt<2; nt++){
      const int col = colbase + nt*16 + m;
      #pragma unroll
      for (int r=0;r<4;r++){
        dst[(quad*4+r)*132 + col]    = acc[0][nt][r];
        dst[(16+quad*4+r)*132 + col] = acc[1][nt][r];
      }
    }
  }
  __syncthreads();
  for (int e=t; e<32*132; e+=512) s_gl[e] += s_glB[e];
  if (t < 128) s_p2[t] = s_p2[t] + s_p2[128+t] + s_p2[256+t] + s_p2[384+t];
  __syncthreads();

  if (t < 256){
    const int j = t>>3, pq = t&7;
    float sum = 0.f;
    #pragma unroll
    for (int q=0;q<4;q++){
      const int c = pq*16 + q*4;
      const float4 g = *(const float4*)&s_gl[j*132 + c];
      const float4 r = *(const float4*)&s_p2[c];
      const float4 a = *(const float4*)&s_at[c];
      float e0 = r.x+g.x; e0 = fmaxf(e0, 0.2f*e0);
      float e1 = r.y+g.y; e1 = fmaxf(e1, 0.2f*e1);
      float e2 = r.z+g.z; e2 = fmaxf(e2, 0.2f*e2);
      float e3 = r.w+g.w; e3 = fmaxf(e3, 0.2f*e3);
      sum += e0*a.x + e1*a.y + e2*a.z + e3*a.w;
    }
    sum += __shfl_xor(sum,1,64);
    sum += __shfl_xor(sum,2,64);
    sum += __shfl_xor(sum,4,64);
    if (pq==0) s_lg[j] = sum;
  }
  __syncthreads();
  if (t < 32){
    const float lg = s_lg[t];
    const bool ok = (arow>>t)&1u;
    float v = ok ? lg : -3.0e38f;
    #pragma unroll
    for (int d_=16; d_; d_>>=1) v = fmaxf(v, __shfl_xor(v, d_, 32));
    const float e = ok ? __expf(lg - v) : 0.f;
    float sm = e;
    #pragma unroll
    for (int d_=16; d_; d_>>=1) sm += __shfl_xor(sm, d_, 32);
    s_al[t] = e / sm;
  }
  __syncthreads();
  if (t < 128){
    float acc2 = 0.f;
    #pragma unroll 8
    for (int j=0;j<32;j++) acc2 += s_al[j] * s_gl[j*132 + t];
    const float x3v = fmaxf(acc2 + s_bb[t], 0.f);
    const int kk = 640 + h*128 + t;
    xcatpk[(size_t)(s>>4)*18432 + (kk>>5)*512 + (s&15)*32 + (kk&31)] = packbf(x3v);
    s_xt[t] = x3v;   // s_xt free after grt partial; reuse for x3 slice
  }
  __syncthreads();

  // x3 contribution to heads layer-1 (fp32 GEMV): col = t (0..255 q, 256..511 v)
  {
    const float* W; int col;
    if (t < 256){ W = q_w1f; col = t; }
    else        { W = v_w1f; col = t-256; }
    const float* wp = W + (size_t)(640 + h*128)*256 + col;
    float acc3 = 0.f;
    #pragma unroll 8
    for (int k=0;k<128;k++) acc3 += s_xt[k] * wp[(size_t)k*256];
    hp3[((size_t)h*128 + s)*512 + t] = acc3;
  }
}

// =============== K4: heads epilogue (sum 4 hpart + 4 hp3) + final combine ===============
__global__ __launch_bounds__(256) void hepi_kernel(
    const float* __restrict__ hpart, const float* __restrict__ hp3,
    const float* __restrict__ q_b1, const float* __restrict__ q_w2, const float* __restrict__ q_b2,
    const float* __restrict__ v_b1, const float* __restrict__ v_w2, const float* __restrict__ v_b2,
    float* __restrict__ out)
{
  __shared__ float s_p[4*6];
  const int t = threadIdx.x, s = blockIdx.x;
  float hq = q_b1[t], hv = v_b1[t];
  #pragma unroll
  for (int ks=0; ks<4; ks++){
    hq += hpart[(size_t)ks*65536 + (size_t)s*512 + t];
    hv += hpart[(size_t)ks*65536 + (size_t)s*512 + 256 + t];
  }
  #pragma unroll
  for (int h=0; h<4; h++){
    hq += hp3[((size_t)h*128 + s)*512 + t];
    hv += hp3[((size_t)h*128 + s)*512 + 256 + t];
  }
  hq = fmaxf(hq, 0.f);
  hv = fmaxf(hv, 0.f);
  float p[6];
  #pragma unroll
  for (int o=0;o<5;o++) p[o] = hq * q_w2[t*5+o];
  p[5] = hv * v_w2[t];
  #pragma unroll
  for (int d_=32; d_; d_>>=1){
    #pragma unroll
    for (int o=0;o<6;o++) p[o] += __shfl_xor(p[o], d_, 64);
  }
  const int w = t>>6, lane = t&63;
  if (lane==0){
    #pragma unroll
    for (int o=0;o<6;o++) s_p[w*6+o] = p[o];
  }
  __syncthreads();
  if (t < 6) s_p[t] = s_p[t] + s_p[6+t] + s_p[12+t] + s_p[18+t];
  __syncthreads();
  if (t < 5){
    const float q0 = s_p[0]+q_b2[0], q1 = s_p[1]+q_b2[1], q2 = s_p[2]+q_b2[2],
                q3 = s_p[3]+q_b2[3], q4 = s_p[4]+q_b2[4];
    const float mean = (q0+q1+q2+q3+q4) / 5.0f;
    const float v = s_p[5] + v_b2[0];
    const float qt = (t==0?q0:t==1?q1:t==2?q2:t==3?q3:q4);
    out[s*5+t] = qt - mean + v;
  }
}

extern "C" void kernel_launch(void* const* d_in, const int* in_sizes, int n_in,
                              void* d_out, int out_size, void* d_ws, size_t ws_size,
                              hipStream_t stream) {
  (void)n_in; (void)out_size; (void)ws_size;
  const float* obs    = (const float*)d_in[0];
  const float* enc_w1 = (const float*)d_in[1];
  const float* enc_b1 = (const float*)d_in[2];
  const float* enc_w2 = (const float*)d_in[3];
  const float* enc_b2 = (const float*)d_in[4];
  const float* wl1    = (const float*)d_in[5];
  const float* wr1    = (const float*)d_in[6];
  const float* att1   = (const float*)d_in[7];
  const float* bias1  = (const float*)d_in[8];
  const float* wl2    = (const float*)d_in[9];
  const float* wr2    = (const float*)d_in[10];
  const float* att2   = (const float*)d_in[11];
  const float* bias2  = (const float*)d_in[12];
  const float* q_w1   = (const float*)d_in[13];
  const float* q_b1   = (const float*)d_in[14];
  const float* q_w2   = (const float*)d_in[15];
  const float* q_b2   = (const float*)d_in[16];
  const float* v_w1   = (const float*)d_in[17];
  const float* v_b1   = (const float*)d_in[18];
  const float* v_w2   = (const float*)d_in[19];
  const float* v_b2   = (const float*)d_in[20];

  char* ws = (char*)d_ws;
  uint_t*   x_pk    = (uint_t*)  (ws + 0);
  uint_t*   xcat_pk = (uint_t*)  (ws + 2097152);
  unsigned* adjw    = (unsigned*)(ws + 2686976);
  int*      aiw     = (int*)     (ws + 2703360);
  uint_t*   x2_pk   = (uint_t*)  (ws + 2703872);
  ushort_t* wl1Thi  = (ushort_t*)(ws + 11092480);
  ushort_t* wl1Tlo  = (ushort_t*)(ws + 11223552);
  ushort_t* wr1Thi  = (ushort_t*)(ws + 11354624);
  ushort_t* wr1Tlo  = (ushort_t*)(ws + 11485696);
  ushort_t* wl2Thi  = (ushort_t*)(ws + 11616768);
  ushort_t* wl2Tlo  = (ushort_t*)(ws + 12141056);
  ushort_t* qw1Thi  = (ushort_t*)(ws + 12665344);
  ushort_t* qw1Tlo  = (ushort_t*)(ws + 13255168);
  ushort_t* vw1Thi  = (ushort_t*)(ws + 13844992);
  ushort_t* vw1Tlo  = (ushort_t*)(ws + 14434816);
  float*    hpart   = (float*)   (ws + 15024640);   // 4*65536*4 = 1,048,576
  float*    hp3     = (float*)   (ws + 16073216);   // 4*128*512*4 = 1,048,576

  const int bs = in_sizes[0] / 577;   // 128

  // K1: enc (512 blocks) + wl1/wr1 converts (128 blocks)
  prep_kernel<<<512 + 128, 256, 0, stream>>>(obs, enc_w1, enc_b1, enc_w2, enc_b2,
      wl1, wr1, wl1Thi, wl1Tlo, wr1Thi, wr1Tlo,
      x_pk, xcat_pk, adjw, aiw);

  // K2: pa1 (512 blocks) + wl2/qw1/vw1 converts (832 blocks)
  pa1_kernel<<<512 + 832, 512, 0, stream>>>(x_pk, wl1Thi, wl1Tlo, wr1Thi, wr1Tlo,
      att1, bias1, adjw, aiw,
      wl2, q_w1, v_w1, wl2Thi, wl2Tlo, qw1Thi, qw1Tlo, vw1Thi, vw1Tlo,
      x2_pk, xcat_pk);

  // K3: pa2 (512) + heads x1/x2 partials ks0..3 (32), x3 partials computed in-block
  pa2_kernel<<<512 + 32, 512, 0, stream>>>(x2_pk, wl2Thi, wl2Tlo, wr2,
      att2, bias2, adjw, aiw,
      qw1Thi, qw1Tlo, vw1Thi, vw1Tlo, q_w1, v_w1, hpart, hp3, xcat_pk);

  // K4: epilogue
  hepi_kernel<<<bs, 256, 0, stream>>>(hpart, hp3, q_b1, q_w2, q_b2, v_b1, v_w2, v_b2,
                                      (float*)d_out);
}

// Round 15
// 173.838 us; speedup vs baseline: 1.2183x; 1.0099x over previous
//
#include <hip/hip_runtime.h>
#include <hip/hip_bf16.h>

typedef unsigned int uint_t;
typedef unsigned short ushort_t;
typedef __attribute__((ext_vector_type(8))) short short8;
typedef __attribute__((ext_vector_type(4))) float floatx4;

__device__ __forceinline__ float4 fma4(float4 a, float s, float4 w){
  a.x += s*w.x; a.y += s*w.y; a.z += s*w.z; a.w += s*w.w; return a;
}
__device__ __forceinline__ float4 relu4(float4 a){
  return make_float4(fmaxf(a.x,0.f),fmaxf(a.y,0.f),fmaxf(a.z,0.f),fmaxf(a.w,0.f));
}
__device__ __forceinline__ unsigned bf16rne(float f){
  unsigned u = __float_as_uint(f);
  return (u + 0x7fffu + ((u>>16)&1u)) >> 16;
}
__device__ __forceinline__ uint_t packbf(float f){
  unsigned hb = bf16rne(f);
  float hf = __uint_as_float(hb<<16);
  unsigned lb = bf16rne(f - hf);
  return (hb<<16) | lb;
}
__device__ __forceinline__ uint4 pack4(float4 v){
  uint4 u; u.x=packbf(v.x); u.y=packbf(v.y); u.z=packbf(v.z); u.w=packbf(v.w); return u;
}
__device__ __forceinline__ float unpk(uint_t u){
  return __uint_as_float(u & 0xffff0000u) + __uint_as_float(u<<16);
}
#define UNPACK8(u0,u1,hi,lo) \
  hi[0]=(short)(u0.x>>16); lo[0]=(short)u0.x; \
  hi[1]=(short)(u0.y>>16); lo[1]=(short)u0.y; \
  hi[2]=(short)(u0.z>>16); lo[2]=(short)u0.z; \
  hi[3]=(short)(u0.w>>16); lo[3]=(short)u0.w; \
  hi[4]=(short)(u1.x>>16); lo[4]=(short)u1.x; \
  hi[5]=(short)(u1.y>>16); lo[5]=(short)u1.y; \
  hi[6]=(short)(u1.z>>16); lo[6]=(short)u1.z; \
  hi[7]=(short)(u1.w>>16); lo[7]=(short)u1.w;

// Fragment-order offset: off(n,k) = (n>>4)*16*K + (k>>5)*512 + (n&15)*32 + (k&31)

// heads GEMM K-split body: job (ks in 0..3, ct in 0..7), 512 threads (8 waves = 8 row-blocks).
__device__ __forceinline__ void hgemm_body(
    const uint_t* __restrict__ xcatpk,
    const ushort_t* __restrict__ qw1Thi, const ushort_t* __restrict__ qw1Tlo,
    const ushort_t* __restrict__ vw1Thi, const ushort_t* __restrict__ vw1Tlo,
    float* __restrict__ part, int ks, int ct, int t)
{
  const int w = t>>6, lane = t&63, m = lane&15, quad = lane>>4;
  const ushort_t* Bhi = (ct<4) ? qw1Thi : vw1Thi;
  const int cbl = (ct<4) ? ct*64 : (ct-4)*64;
  const int cbg = (ct<4) ? ct*64 : 256 + (ct-4)*64;
  const uint_t* ap = xcatpk + (size_t)w*18432 + m*32 + quad*8 + (size_t)(ks*5)*512;
  const ushort_t* bp0 = Bhi + (size_t)((cbl>>4)+0)*18432 + m*32 + quad*8 + (size_t)(ks*5)*512;
  const ushort_t* bp1 = Bhi + (size_t)((cbl>>4)+1)*18432 + m*32 + quad*8 + (size_t)(ks*5)*512;
  const ushort_t* bp2 = Bhi + (size_t)((cbl>>4)+2)*18432 + m*32 + quad*8 + (size_t)(ks*5)*512;
  const ushort_t* bp3 = Bhi + (size_t)((cbl>>4)+3)*18432 + m*32 + quad*8 + (size_t)(ks*5)*512;
  const size_t lod = (size_t)(qw1Tlo - qw1Thi);
  floatx4 acc[4];
  #pragma unroll
  for (int i=0;i<4;i++) acc[i] = (floatx4){0.f,0.f,0.f,0.f};
  #pragma unroll
  for (int kc=0; kc<5; kc++){
    const uint4 ua0 = *(const uint4*)(ap);
    const uint4 ua1 = *(const uint4*)(ap+4);
    ap += 512;
    short8 ahi, alo;
    UNPACK8(ua0,ua1,ahi,alo)
    const ushort_t* bps[4] = {bp0, bp1, bp2, bp3};
    #pragma unroll
    for (int nt=0; nt<4; nt++){
      const short8 bh = *(const short8*)(bps[nt] + kc*512);
      const short8 bl = *(const short8*)(bps[nt] + kc*512 + lod);
      acc[nt] = __builtin_amdgcn_mfma_f32_16x16x32_bf16(ahi, bh, acc[nt], 0,0,0);
      acc[nt] = __builtin_amdgcn_mfma_f32_16x16x32_bf16(ahi, bl, acc[nt], 0,0,0);
      acc[nt] = __builtin_amdgcn_mfma_f32_16x16x32_bf16(alo, bh, acc[nt], 0,0,0);
    }
  }
  float* pdst = part + (size_t)ks*65536;
  const int crow0 = w*16 + quad*4;
  #pragma unroll
  for (int nt=0; nt<4; nt++){
    const int col = cbg + nt*16 + m;
    #pragma unroll
    for (int r=0;r<4;r++)
      pdst[(size_t)(crow0 + r)*512 + col] = acc[nt][r];
  }
}

// =============== K1: enc (blocks 0..511, XCD-swizzled) + wl1/wr1 convert (512..639) ===============
__global__ __launch_bounds__(256) void prep_kernel(
    const float* __restrict__ obs,
    const float* __restrict__ enc_w1, const float* __restrict__ enc_b1,
    const float* __restrict__ enc_w2, const float* __restrict__ enc_b2,
    const float* __restrict__ wl1, const float* __restrict__ wr1,
    ushort_t* __restrict__ wl1Thi, ushort_t* __restrict__ wl1Tlo,
    ushort_t* __restrict__ wr1Thi, ushort_t* __restrict__ wr1Tlo,
    uint_t* __restrict__ xpk, uint_t* __restrict__ xcatpk,
    unsigned* __restrict__ adjw, int* __restrict__ aiw)
{
  const int t = threadIdx.x, bid = blockIdx.x;
  if (bid >= 512){
    __shared__ float sm[32][33];
    const int cw = bid - 512;
    const float* in; ushort_t* ohi; ushort_t* olo; int tt;
    const int K = 128, N = 512;
    if (cw < 64){ in=wl1; ohi=wl1Thi; olo=wl1Tlo; tt=cw; }
    else        { in=wr1; ohi=wr1Thi; olo=wr1Tlo; tt=cw-64; }
    const int ktiles = K>>5;
    const int kt = tt % ktiles, nt = tt / ktiles;
    const int r = t>>5, c = t&31;
    #pragma unroll
    for (int i=0;i<4;i++)
      sm[r+i*8][c] = in[(size_t)(kt*32 + r + i*8)*N + nt*32 + c];
    __syncthreads();
    #pragma unroll
    for (int i=0;i<4;i++){
      const int nl = r + i*8;
      const int n  = nt*32 + nl;
      const float f = sm[c][nl];
      const unsigned hb = bf16rne(f);
      const float hf = __uint_as_float(hb<<16);
      const unsigned lb = bf16rne(f - hf);
      const size_t off = (size_t)(n>>4)*(16*K) + (size_t)kt*512 + (size_t)(n&15)*32 + c;
      ohi[off] = (ushort_t)hb;
      olo[off] = (ushort_t)lb;
    }
    return;
  }
  __shared__ float s_pos[64];
  __shared__ float s_feats[128];
  __shared__ __align__(16) float s_h[8*132];
  __shared__ int s_ai;
  // XCD swizzle: same-sample blocks 128 apart -> same XCD (bid%8 preserved)
  const int s = bid & 127, g = bid >> 7;
  const float* ob = obs + s*577;

  if (t==0){
    float a = ob[576];
    a = fminf(fmaxf(a, 0.f), 31.f);
    s_ai = (int)a;
    if (g==0) aiw[s] = (int)a;
  }
  if (t < 128){ const int n=t>>4, f=t&15; s_feats[t] = ob[(g*8+n)*18+2+f]; }
  if (g==0 && t>=128 && t<192){ const int u=t-128; s_pos[u] = ob[(u>>1)*18 + (u&1)]; }
  __syncthreads();

  if (g==0 && t < 32){
    const float px = s_pos[2*t], py = s_pos[2*t+1];
    const float R2 = 0.09f;
    unsigned mm = 0u;
    for (int j=0;j<32;j++){
      const float dx = __fsub_rn(px, s_pos[2*j]), dy = __fsub_rn(py, s_pos[2*j+1]);
      const float d2 = __fadd_rn(__fmul_rn(dx,dx), __fmul_rn(dy,dy));
      if (d2 <= R2 || j==t) mm |= (1u<<j);
    }
    adjw[s*32+t] = mm;
  }

  const int n = t>>5, c0 = (t&31)*4;
  {
    float4 a = *(const float4*)(enc_b1+c0);
    #pragma unroll
    for (int f=0; f<16; f++)
      a = fma4(a, s_feats[n*16+f], *(const float4*)(enc_w1 + f*128 + c0));
    *(float4*)&s_h[n*132+c0] = relu4(a);
  }
  __syncthreads();
  {
    float4 a = *(const float4*)(enc_b2+c0);
    for (int k=0;k<128;k+=4){
      const float4 hv = *(const float4*)&s_h[n*132+k];
      a = fma4(a, hv.x, *(const float4*)(enc_w2 + (k+0)*128 + c0));
      a = fma4(a, hv.y, *(const float4*)(enc_w2 + (k+1)*128 + c0));
      a = fma4(a, hv.z, *(const float4*)(enc_w2 + (k+2)*128 + c0));
      a = fma4(a, hv.w, *(const float4*)(enc_w2 + (k+3)*128 + c0));
    }
    a = relu4(a);
    const uint4 p = pack4(a);
    const int i = g*8 + n;
    uint_t* xp = xpk + (size_t)(s*2 + (i>>4))*2048 + (c0>>5)*512 + (i&15)*32 + (c0&31);
    *(uint4*)xp = p;
    if (i == s_ai){
      uint_t* xc = xcatpk + (size_t)(s>>4)*18432 + (c0>>5)*512 + (s&15)*32 + (c0&31);
      *(uint4*)xc = p;
    }
  }
}

// =============== K2: pa1 (blocks 0..511, XCD-swizzled) + converts (512..1343) ===============
__global__ __launch_bounds__(512) void pa1_kernel(
    const uint_t* __restrict__ xpk,
    const ushort_t* __restrict__ wl1Thi, const ushort_t* __restrict__ wl1Tlo,
    const ushort_t* __restrict__ wr1Thi, const ushort_t* __restrict__ wr1Tlo,
    const float* __restrict__ att, const float* __restrict__ bias,
    const unsigned* __restrict__ adjw, const int* __restrict__ aiw,
    const float* __restrict__ wl2, const float* __restrict__ q_w1, const float* __restrict__ v_w1,
    ushort_t* __restrict__ wl2Thi, ushort_t* __restrict__ wl2Tlo,
    ushort_t* __restrict__ qw1Thi, ushort_t* __restrict__ qw1Tlo,
    ushort_t* __restrict__ vw1Thi, ushort_t* __restrict__ vw1Tlo,
    uint_t* __restrict__ x2pk, uint_t* __restrict__ xcatpk)
{
  __shared__ __align__(16) float s_gl[32*132];
  __shared__ __align__(16) float s_glB[32*132];
  __shared__ __align__(16) float s_gr[32*132];
  __shared__ __align__(16) float s_grB[32*132];
  __shared__ __align__(16) float s_att[128];
  __shared__ __align__(16) float s_b[128];
  __shared__ float s_lg[32*33];
  __shared__ unsigned s_adj[32];
  const int t = threadIdx.x, bid = blockIdx.x;

  if (bid >= 512){
    const int cw = bid - 512;
    const float* in; ushort_t* ohi; ushort_t* olo; int K, N, tt;
    if (cw < 256)      { in=wl2;  ohi=wl2Thi; olo=wl2Tlo; K=512;  N=512; tt=cw; }
    else if (cw < 544) { in=q_w1; ohi=qw1Thi; olo=qw1Tlo; K=1152; N=256; tt=cw-256; }
    else               { in=v_w1; ohi=vw1Thi; olo=vw1Tlo; K=1152; N=256; tt=cw-544; }
    const int ktiles = K>>5;
    const int kt = tt % ktiles, nt = tt / ktiles;
    const int r = t>>5, c = t&31;   // r in [0,16)
    #pragma unroll
    for (int i=0;i<2;i++)
      s_gl[(r+i*16)*33 + c] = in[(size_t)(kt*32 + r + i*16)*N + nt*32 + c];
    __syncthreads();
    #pragma unroll
    for (int i=0;i<2;i++){
      const int nl = r + i*16;
      const int n  = nt*32 + nl;
      const float f = s_gl[c*33 + nl];
      const unsigned hb = bf16rne(f);
      const float hf = __uint_as_float(hb<<16);
      const unsigned lb = bf16rne(f - hf);
      const size_t off = (size_t)(n>>4)*(16*K) + (size_t)kt*512 + (size_t)(n&15)*32 + c;
      ohi[off] = (ushort_t)hb;
      olo[off] = (ushort_t)lb;
    }
    return;
  }

  // XCD swizzle: same-sample blocks 128 apart -> same XCD
  const int s = bid & 127, h = bid >> 7;
  const int w = t>>6, lane = t&63, m = lane&15, quad = lane>>4;
  const int ww = w&3, khalf = w>>2;

  if (t < 128){ s_att[t] = att[h*128 + t]; s_b[t] = bias[h*128 + t]; }
  if (t >= 224 && t < 256) s_adj[t-224] = adjw[s*32 + (t-224)];
  const int ai = aiw[s];

  const ushort_t* Bhi = (ww<2) ? wl1Thi : wr1Thi;
  const ushort_t* Blo = (ww<2) ? wl1Tlo : wr1Tlo;
  const int nbase = h*8 + (ww&1)*4;
  const int kcb = khalf*2;
  const uint_t* a0p = xpk + (size_t)(s*2+0)*2048 + m*32 + quad*8 + kcb*512;
  const uint_t* a1p = xpk + (size_t)(s*2+1)*2048 + m*32 + quad*8 + kcb*512;
  const ushort_t* bp0 = Bhi + (size_t)(nbase+0)*2048 + m*32 + quad*8 + kcb*512;
  const ushort_t* bp1 = Bhi + (size_t)(nbase+1)*2048 + m*32 + quad*8 + kcb*512;
  const ushort_t* bp2 = Bhi + (size_t)(nbase+2)*2048 + m*32 + quad*8 + kcb*512;
  const ushort_t* bp3 = Bhi + (size_t)(nbase+3)*2048 + m*32 + quad*8 + kcb*512;
  const size_t lod = (size_t)(Blo - Bhi);
  floatx4 acc[2][4];
  #pragma unroll
  for (int i=0;i<2;i++)
    #pragma unroll
    for (int j=0;j<4;j++) acc[i][j] = (floatx4){0.f,0.f,0.f,0.f};

  #pragma unroll
  for (int kc=0; kc<2; kc++){
    const uint4 u00 = *(const uint4*)(a0p + kc*512);
    const uint4 u01 = *(const uint4*)(a0p + kc*512 + 4);
    const uint4 u10 = *(const uint4*)(a1p + kc*512);
    const uint4 u11 = *(const uint4*)(a1p + kc*512 + 4);
    short8 ahi0, alo0, ahi1, alo1;
    UNPACK8(u00,u01,ahi0,alo0)
    UNPACK8(u10,u11,ahi1,alo1)
    const ushort_t* bps[4] = {bp0, bp1, bp2, bp3};
    #pragma unroll
    for (int nt=0; nt<4; nt++){
      const short8 bh = *(const short8*)(bps[nt] + kc*512);
      const short8 bl = *(const short8*)(bps[nt] + kc*512 + lod);
      acc[0][nt] = __builtin_amdgcn_mfma_f32_16x16x32_bf16(ahi0, bh, acc[0][nt], 0,0,0);
      acc[0][nt] = __builtin_amdgcn_mfma_f32_16x16x32_bf16(ahi0, bl, acc[0][nt], 0,0,0);
      acc[0][nt] = __builtin_amdgcn_mfma_f32_16x16x32_bf16(alo0, bh, acc[0][nt], 0,0,0);
      acc[1][nt] = __builtin_amdgcn_mfma_f32_16x16x32_bf16(ahi1, bh, acc[1][nt], 0,0,0);
      acc[1][nt] = __builtin_amdgcn_mfma_f32_16x16x32_bf16(ahi1, bl, acc[1][nt], 0,0,0);
      acc[1][nt] = __builtin_amdgcn_mfma_f32_16x16x32_bf16(alo1, bh, acc[1][nt], 0,0,0);
    }
  }
  {
    float* dst = (ww<2) ? (khalf ? s_glB : s_gl) : (khalf ? s_grB : s_gr);
    const int colbase = (ww&1)*64;
    #pragma unroll
    for (int nt=0; nt<4; nt++){
      const int col = colbase + nt*16 + m;
      #pragma unroll
      for (int r=0;r<4;r++){
        dst[(quad*4+r)*132 + col]      = acc[0][nt][r];
        dst[(16+quad*4+r)*132 + col]   = acc[1][nt][r];
      }
    }
  }
  __syncthreads();
  for (int e=t; e<32*132; e+=512){
    s_gl[e] += s_glB[e];
    s_gr[e] += s_grB[e];
  }
  __syncthreads();

  // logits
  {
    const int i = t>>4, jb = t&15;
    float lacc[2] = {0.f,0.f};
    for (int c=0;c<128;c+=4){
      const float4 g = *(const float4*)&s_gr[i*132+c];
      const float4 a = *(const float4*)&s_att[c];
      #pragma unroll
      for (int mm=0;mm<2;mm++){
        const float4 gj = *(const float4*)&s_gl[(jb+16*mm)*132 + c];
        float ex = g.x+gj.x; ex = fmaxf(ex, 0.2f*ex);
        float ey = g.y+gj.y; ey = fmaxf(ey, 0.2f*ey);
        float ez = g.z+gj.z; ez = fmaxf(ez, 0.2f*ez);
        float ew = g.w+gj.w; ew = fmaxf(ew, 0.2f*ew);
        lacc[mm] += ex*a.x + ey*a.y + ez*a.z + ew*a.w;
      }
    }
    s_lg[i*33 + jb]      = lacc[0];
    s_lg[i*33 + jb + 16] = lacc[1];
  }
  __syncthreads();

  // masked softmax
  #pragma unroll
  for (int rnd=0; rnd<2; rnd++){
    const int i = rnd*16 + (t>>5), j = t&31;
    const float lg = s_lg[i*33+j];
    const bool ok = (s_adj[i]>>j)&1u;
    float v = ok ? lg : -3.0e38f;
    #pragma unroll
    for (int d_=16; d_; d_>>=1) v = fmaxf(v, __shfl_xor(v, d_, 32));
    const float e = ok ? __expf(lg - v) : 0.f;
    float sum = e;
    #pragma unroll
    for (int d_=16; d_; d_>>=1) sum += __shfl_xor(sum, d_, 32);
    s_lg[i*33+j] = e / sum;
  }
  __syncthreads();

  // aggregate -> packed x2 + tap
  {
    const int i = t>>4, c0 = (t&15)*8;
    float4 o0 = make_float4(0.f,0.f,0.f,0.f), o1 = o0;
    for (int j=0;j<32;j++){
      const float al = s_lg[i*33+j];
      o0 = fma4(o0, al, *(const float4*)&s_gl[j*132 + c0]);
      o1 = fma4(o1, al, *(const float4*)&s_gl[j*132 + c0 + 4]);
    }
    const float4 b0 = *(const float4*)&s_b[c0];
    const float4 b1 = *(const float4*)&s_b[c0+4];
    o0 = relu4(make_float4(o0.x+b0.x, o0.y+b0.y, o0.z+b0.z, o0.w+b0.w));
    o1 = relu4(make_float4(o1.x+b1.x, o1.y+b1.y, o1.z+b1.z, o1.w+b1.w));
    const uint4 p0 = pack4(o0), p1 = pack4(o1);
    const int kb = h*128 + c0;
    uint_t* xp = x2pk + (size_t)(s*2 + (i>>4))*8192 + (kb>>5)*512 + (i&15)*32 + (kb&31);
    *(uint4*)&xp[0] = p0;
    *(uint4*)&xp[4] = p1;
    if (i == ai){
      const int kk = 128 + kb;
      uint_t* tp = xcatpk + (size_t)(s>>4)*18432 + (kk>>5)*512 + (s&15)*32 + (kk&31);
      *(uint4*)&tp[0] = p0;
      *(uint4*)&tp[4] = p1;
    }
  }
}

// =============== K3: pa2 (0..511, XCD-swizzled) + heads-GEMM x1/x2 partials (512..543) ===============
__global__ __launch_bounds__(512) void pa2_kernel(
    const uint_t* __restrict__ x2pk,
    const ushort_t* __restrict__ wl2Thi, const ushort_t* __restrict__ wl2Tlo,
    const float* __restrict__ wr2f,
    const float* __restrict__ att2, const float* __restrict__ bias2,
    const unsigned* __restrict__ adjw, const int* __restrict__ aiw,
    const ushort_t* __restrict__ qw1Thi, const ushort_t* __restrict__ qw1Tlo,
    const ushort_t* __restrict__ vw1Thi, const ushort_t* __restrict__ vw1Tlo,
    const float* __restrict__ q_w1f, const float* __restrict__ v_w1f,
    float* __restrict__ hpart, float* __restrict__ hp3,
    uint_t* __restrict__ xcatpk)
{
  const int t = threadIdx.x, bid = blockIdx.x;
  if (bid >= 512){
    const int hk = bid - 512;     // 0..31: ks = hk>>3 (0..3), ct = hk&7
    hgemm_body(xcatpk, qw1Thi, qw1Tlo, vw1Thi, vw1Tlo, hpart, hk>>3, hk&7, t);
    return;
  }
  __shared__ __align__(16) float s_gl[32*132];
  __shared__ __align__(16) float s_glB[32*132];
  __shared__ __align__(16) float s_xt[512];
  __shared__ __align__(16) float s_p2[4*128];
  __shared__ __align__(16) float s_at[128];
  __shared__ __align__(16) float s_bb[128];
  __shared__ float s_lg[32];
  __shared__ float s_al[32];
  // XCD swizzle: same-sample blocks 128 apart -> same XCD
  const int s = bid & 127, h = bid >> 7;
  const int w = t>>6, lane = t&63, m = lane&15, quad = lane>>4;
  const int ww = w&3, khalf = w>>2;
  const int ai = aiw[s];
  const unsigned arow = adjw[s*32+ai];

  {
    const int kk = 128 + t;
    s_xt[t] = unpk(xcatpk[(size_t)(s>>4)*18432 + (kk>>5)*512 + (s&15)*32 + (kk&31)]);
  }
  if (t < 128){ s_at[t] = att2[h*128+t]; s_bb[t] = bias2[h*128+t]; }
  __syncthreads();

  // grt partial (4-way K split)
  {
    const int c = t&127, q4 = t>>7;
    const float* wp = wr2f + (size_t)(q4*128)*512 + h*128 + c;
    float ga = 0.f;
    #pragma unroll 8
    for (int k=0;k<128;k++) ga += s_xt[q4*128 + k] * wp[(size_t)k*512];
    s_p2[q4*128 + c] = ga;
  }

  const int kcb = khalf*8;
  const uint_t* a0p = x2pk + (size_t)(s*2+0)*8192 + m*32 + quad*8 + kcb*512;
  const uint_t* a1p = x2pk + (size_t)(s*2+1)*8192 + m*32 + quad*8 + kcb*512;
  const ushort_t* bq0 = wl2Thi + (size_t)(h*8 + ww*2+0)*8192 + m*32 + quad*8 + kcb*512;
  const ushort_t* bq1 = wl2Thi + (size_t)(h*8 + ww*2+1)*8192 + m*32 + quad*8 + kcb*512;
  const size_t lod = (size_t)(wl2Tlo - wl2Thi);
  floatx4 acc[2][2];
  #pragma unroll
  for (int i=0;i<2;i++){ acc[i][0] = (floatx4){0.f,0.f,0.f,0.f}; acc[i][1] = acc[i][0]; }
  #pragma unroll 4
  for (int kc=0; kc<8; kc++){
    const uint4 u00 = *(const uint4*)(a0p + kc*512);
    const uint4 u01 = *(const uint4*)(a0p + kc*512 + 4);
    const uint4 u10 = *(const uint4*)(a1p + kc*512);
    const uint4 u11 = *(const uint4*)(a1p + kc*512 + 4);
    short8 ahi0, alo0, ahi1, alo1;
    UNPACK8(u00,u01,ahi0,alo0)
    UNPACK8(u10,u11,ahi1,alo1)
    {
      const short8 bh = *(const short8*)(bq0 + kc*512);
      const short8 bl = *(const short8*)(bq0 + kc*512 + lod);
      acc[0][0] = __builtin_amdgcn_mfma_f32_16x16x32_bf16(ahi0, bh, acc[0][0], 0,0,0);
      acc[0][0] = __builtin_amdgcn_mfma_f32_16x16x32_bf16(ahi0, bl, acc[0][0], 0,0,0);
      acc[0][0] = __builtin_amdgcn_mfma_f32_16x16x32_bf16(alo0, bh, acc[0][0], 0,0,0);
      acc[1][0] = __builtin_amdgcn_mfma_f32_16x16x32_bf16(ahi1, bh, acc[1][0], 0,0,0);
      acc[1][0] = __builtin_amdgcn_mfma_f32_16x16x32_bf16(ahi1, bl, acc[1][0], 0,0,0);
      acc[1][0] = __builtin_amdgcn_mfma_f32_16x16x32_bf16(alo1, bh, acc[1][0], 0,0,0);
    }
    {
      const short8 bh = *(const short8*)(bq1 + kc*512);
      const short8 bl = *(const short8*)(bq1 + kc*512 + lod);
      acc[0][1] = __builtin_amdgcn_mfma_f32_16x16x32_bf16(ahi0, bh, acc[0][1], 0,0,0);
      acc[0][1] = __builtin_amdgcn_mfma_f32_16x16x32_bf16(ahi0, bl, acc[0][1], 0,0,0);
      acc[0][1] = __builtin_amdgcn_mfma_f32_16x16x32_bf16(alo0, bh, acc[0][1], 0,0,0);
      acc[1][1] = __builtin_amdgcn_mfma_f32_16x16x32_bf16(ahi1, bh, acc[1][1], 0,0,0);
      acc[1][1] = __builtin_amdgcn_mfma_f32_16x16x32_bf16(ahi1, bl, acc[1][1], 0,0,0);
      acc[1][1] = __builtin_amdgcn_mfma_f32_16x16x32_bf16(alo1, bh, acc[1][1], 0,0,0);
    }
  }
  {
    float* dst = khalf ? s_glB : s_gl;
    const int colbase = ww*32;
    #pragma unroll
    for (int nt=0; nt<2; nt++){
      const int col = colbase + nt*16 + m;
      #pragma unroll
      for (int r=0;r<4;r++){
        dst[(quad*4+r)*132 + col]    = acc[0][nt][r];
        dst[(16+quad*4+r)*132 + col] = acc[1][nt][r];
      }
    }
  }
  __syncthreads();
  for (int e=t; e<32*132; e+=512) s_gl[e] += s_glB[e];
  if (t < 128) s_p2[t] = s_p2[t] + s_p2[128+t] + s_p2[256+t] + s_p2[384+t];
  __syncthreads();

  if (t < 256){
    const int j = t>>3, pq = t&7;
    float sum = 0.f;
    #pragma unroll
    for (int q=0;q<4;q++){
      const int c = pq*16 + q*4;
      const float4 g = *(const float4*)&s_gl[j*132 + c];
      const float4 r = *(const float4*)&s_p2[c];
      const float4 a = *(const float4*)&s_at[c];
      float e0 = r.x+g.x; e0 = fmaxf(e0, 0.2f*e0);
      float e1 = r.y+g.y; e1 = fmaxf(e1, 0.2f*e1);
      float e2 = r.z+g.z; e2 = fmaxf(e2, 0.2f*e2);
      float e3 = r.w+g.w; e3 = fmaxf(e3, 0.2f*e3);
      sum += e0*a.x + e1*a.y + e2*a.z + e3*a.w;
    }
    sum += __shfl_xor(sum,1,64);
    sum += __shfl_xor(sum,2,64);
    sum += __shfl_xor(sum,4,64);
    if (pq==0) s_lg[j] = sum;
  }
  __syncthreads();
  if (t < 32){
    const float lg = s_lg[t];
    const bool ok = (arow>>t)&1u;
    float v = ok ? lg : -3.0e38f;
    #pragma unroll
    for (int d_=16; d_; d_>>=1) v = fmaxf(v, __shfl_xor(v, d_, 32));
    const float e = ok ? __expf(lg - v) : 0.f;
    float sm = e;
    #pragma unroll
    for (int d_=16; d_; d_>>=1) sm += __shfl_xor(sm, d_, 32);
    s_al[t] = e / sm;
  }
  __syncthreads();
  if (t < 128){
    float acc2 = 0.f;
    #pragma unroll 8
    for (int j=0;j<32;j++) acc2 += s_al[j] * s_gl[j*132 + t];
    const float x3v = fmaxf(acc2 + s_bb[t], 0.f);
    const int kk = 640 + h*128 + t;
    xcatpk[(size_t)(s>>4)*18432 + (kk>>5)*512 + (s&15)*32 + (kk&31)] = packbf(x3v);
    s_xt[t] = x3v;   // reuse s_xt for x3 slice
  }
  __syncthreads();

  // x3 contribution to heads layer-1 (fp32 GEMV): col = t (0..255 q, 256..511 v)
  {
    const float* W; int col;
    if (t < 256){ W = q_w1f; col = t; }
    else        { W = v_w1f; col = t-256; }
    const float* wp = W + (size_t)(640 + h*128)*256 + col;
    float acc3 = 0.f;
    #pragma unroll 8
    for (int k=0;k<128;k++) acc3 += s_xt[k] * wp[(size_t)k*256];
    hp3[((size_t)h*128 + s)*512 + t] = acc3;
  }
}

// =============== K4: heads epilogue (sum 4 hpart + 4 hp3) + final combine ===============
__global__ __launch_bounds__(256) void hepi_kernel(
    const float* __restrict__ hpart, const float* __restrict__ hp3,
    const float* __restrict__ q_b1, const float* __restrict__ q_w2, const float* __restrict__ q_b2,
    const float* __restrict__ v_b1, const float* __restrict__ v_w2, const float* __restrict__ v_b2,
    float* __restrict__ out)
{
  __shared__ float s_p[4*6];
  const int t = threadIdx.x, s = blockIdx.x;
  float hq = q_b1[t], hv = v_b1[t];
  #pragma unroll
  for (int ks=0; ks<4; ks++){
    hq += hpart[(size_t)ks*65536 + (size_t)s*512 + t];
    hv += hpart[(size_t)ks*65536 + (size_t)s*512 + 256 + t];
  }
  #pragma unroll
  for (int h=0; h<4; h++){
    hq += hp3[((size_t)h*128 + s)*512 + t];
    hv += hp3[((size_t)h*128 + s)*512 + 256 + t];
  }
  hq = fmaxf(hq, 0.f);
  hv = fmaxf(hv, 0.f);
  float p[6];
  #pragma unroll
  for (int o=0;o<5;o++) p[o] = hq * q_w2[t*5+o];
  p[5] = hv * v_w2[t];
  #pragma unroll
  for (int d_=32; d_; d_>>=1){
    #pragma unroll
    for (int o=0;o<6;o++) p[o] += __shfl_xor(p[o], d_, 64);
  }
  const int w = t>>6, lane = t&63;
  if (lane==0){
    #pragma unroll
    for (int o=0;o<6;o++) s_p[w*6+o] = p[o];
  }
  __syncthreads();
  if (t < 6) s_p[t] = s_p[t] + s_p[6+t] + s_p[12+t] + s_p[18+t];
  __syncthreads();
  if (t < 5){
    const float q0 = s_p[0]+q_b2[0], q1 = s_p[1]+q_b2[1], q2 = s_p[2]+q_b2[2],
                q3 = s_p[3]+q_b2[3], q4 = s_p[4]+q_b2[4];
    const float mean = (q0+q1+q2+q3+q4) / 5.0f;
    const float v = s_p[5] + v_b2[0];
    const float qt = (t==0?q0:t==1?q1:t==2?q2:t==3?q3:q4);
    out[s*5+t] = qt - mean + v;
  }
}

extern "C" void kernel_launch(void* const* d_in, const int* in_sizes, int n_in,
                              void* d_out, int out_size, void* d_ws, size_t ws_size,
                              hipStream_t stream) {
  (void)n_in; (void)out_size; (void)ws_size;
  const float* obs    = (const float*)d_in[0];
  const float* enc_w1 = (const float*)d_in[1];
  const float* enc_b1 = (const float*)d_in[2];
  const float* enc_w2 = (const float*)d_in[3];
  const float* enc_b2 = (const float*)d_in[4];
  const float* wl1    = (const float*)d_in[5];
  const float* wr1    = (const float*)d_in[6];
  const float* att1   = (const float*)d_in[7];
  const float* bias1  = (const float*)d_in[8];
  const float* wl2    = (const float*)d_in[9];
  const float* wr2    = (const float*)d_in[10];
  const float* att2   = (const float*)d_in[11];
  const float* bias2  = (const float*)d_in[12];
  const float* q_w1   = (const float*)d_in[13];
  const float* q_b1   = (const float*)d_in[14];
  const float* q_w2   = (const float*)d_in[15];
  const float* q_b2   = (const float*)d_in[16];
  const float* v_w1   = (const float*)d_in[17];
  const float* v_b1   = (const float*)d_in[18];
  const float* v_w2   = (const float*)d_in[19];
  const float* v_b2   = (const float*)d_in[20];

  char* ws = (char*)d_ws;
  uint_t*   x_pk    = (uint_t*)  (ws + 0);
  uint_t*   xcat_pk = (uint_t*)  (ws + 2097152);
  unsigned* adjw    = (unsigned*)(ws + 2686976);
  int*      aiw     = (int*)     (ws + 2703360);
  uint_t*   x2_pk   = (uint_t*)  (ws + 2703872);
  ushort_t* wl1Thi  = (ushort_t*)(ws + 11092480);
  ushort_t* wl1Tlo  = (ushort_t*)(ws + 11223552);
  ushort_t* wr1Thi  = (ushort_t*)(ws + 11354624);
  ushort_t* wr1Tlo  = (ushort_t*)(ws + 11485696);
  ushort_t* wl2Thi  = (ushort_t*)(ws + 11616768);
  ushort_t* wl2Tlo  = (ushort_t*)(ws + 12141056);
  ushort_t* qw1Thi  = (ushort_t*)(ws + 12665344);
  ushort_t* qw1Tlo  = (ushort_t*)(ws + 13255168);
  ushort_t* vw1Thi  = (ushort_t*)(ws + 13844992);
  ushort_t* vw1Tlo  = (ushort_t*)(ws + 14434816);
  float*    hpart   = (float*)   (ws + 15024640);   // 1,048,576
  float*    hp3     = (float*)   (ws + 16073216);   // 1,048,576

  const int bs = in_sizes[0] / 577;   // 128

  prep_kernel<<<512 + 128, 256, 0, stream>>>(obs, enc_w1, enc_b1, enc_w2, enc_b2,
      wl1, wr1, wl1Thi, wl1Tlo, wr1Thi, wr1Tlo,
      x_pk, xcat_pk, adjw, aiw);

  pa1_kernel<<<512 + 832, 512, 0, stream>>>(x_pk, wl1Thi, wl1Tlo, wr1Thi, wr1Tlo,
      att1, bias1, adjw, aiw,
      wl2, q_w1, v_w1, wl2Thi, wl2Tlo, qw1Thi, qw1Tlo, vw1Thi, vw1Tlo,
      x2_pk, xcat_pk);

  pa2_kernel<<<512 + 32, 512, 0, stream>>>(x2_pk, wl2Thi, wl2Tlo, wr2,
      att2, bias2, adjw, aiw,
      qw1Thi, qw1Tlo, vw1Thi, vw1Tlo, q_w1, v_w1, hpart, hp3, xcat_pk);

  hepi_kernel<<<bs, 256, 0, stream>>>(hpart, hp3, q_b1, q_w2, q_b2, v_b1, v_w2, v_b2,
                                      (float*)d_out);
}